// Round 1
// baseline (814.035 us; speedup 1.0000x reference)
//
#include <hip/hip_runtime.h>
#include <cstddef>

#define B_ 2
#define T_ 2048
#define EMBED_ 1024
#define HEADS_ 16
#define HD_ 64
#define M_ 32
#define R_ 2
#define FD_ 64          // R*M
#define LCH 64          // our chunk length (prefix decomposition is exact for any L)
#define NCH (T_ / LCH)  // 32
#define BH_ (B_ * HEADS_)
#define TW_ 32          // tokens per wave in features kernel

// ---------------------------------------------------------------------------
// GEMM: C[M,N] = A[M,K] @ B[K,N] + bias[N]   (fp32, 128x128 tile, 8x8 micro)
// ---------------------------------------------------------------------------
__global__ __launch_bounds__(256) void gemm_bias_k(
    const float* __restrict__ A, const float* __restrict__ Bm,
    const float* __restrict__ bias, float* __restrict__ C,
    int Mdim, int Ndim, int Kdim, int lda, int ldb, int ldc)
{
  __shared__ float As[16][128];
  __shared__ float Bs[16][128];
  const int tid = threadIdx.x;
  const int row0 = blockIdx.y * 128;
  const int col0 = blockIdx.x * 128;
  const int ty = tid >> 4, tx = tid & 15;
  float acc[8][8];
#pragma unroll
  for (int i = 0; i < 8; ++i)
#pragma unroll
    for (int j = 0; j < 8; ++j) acc[i][j] = 0.f;

  for (int k0 = 0; k0 < Kdim; k0 += 16) {
#pragma unroll
    for (int l = 0; l < 2; ++l) {
      int f = tid * 2 + l;            // 0..511
      int ar = f >> 2, aq = f & 3;    // A tile: 128 rows x 4 float4
      float4 av = *reinterpret_cast<const float4*>(
          &A[(size_t)(row0 + ar) * lda + k0 + aq * 4]);
      As[aq * 4 + 0][ar] = av.x;
      As[aq * 4 + 1][ar] = av.y;
      As[aq * 4 + 2][ar] = av.z;
      As[aq * 4 + 3][ar] = av.w;
      int br = f >> 5, bc = f & 31;   // B tile: 16 rows x 32 float4
      *reinterpret_cast<float4*>(&Bs[br][bc * 4]) =
          *reinterpret_cast<const float4*>(
              &Bm[(size_t)(k0 + br) * ldb + col0 + bc * 4]);
    }
    __syncthreads();
#pragma unroll
    for (int kk = 0; kk < 16; ++kk) {
      float a[8], b[8];
      *reinterpret_cast<float4*>(&a[0]) =
          *reinterpret_cast<const float4*>(&As[kk][ty * 8]);
      *reinterpret_cast<float4*>(&a[4]) =
          *reinterpret_cast<const float4*>(&As[kk][ty * 8 + 4]);
      *reinterpret_cast<float4*>(&b[0]) =
          *reinterpret_cast<const float4*>(&Bs[kk][tx * 8]);
      *reinterpret_cast<float4*>(&b[4]) =
          *reinterpret_cast<const float4*>(&Bs[kk][tx * 8 + 4]);
#pragma unroll
      for (int i = 0; i < 8; ++i)
#pragma unroll
        for (int j = 0; j < 8; ++j) acc[i][j] += a[i] * b[j];
    }
    __syncthreads();
  }
#pragma unroll
  for (int i = 0; i < 8; ++i) {
    int r = row0 + ty * 8 + i;
#pragma unroll
    for (int j = 0; j < 8; j += 4) {
      int c = col0 + tx * 8 + j;
      float4 o;
      o.x = acc[i][j + 0] + bias[c + 0];
      o.y = acc[i][j + 1] + bias[c + 1];
      o.z = acc[i][j + 2] + bias[c + 2];
      o.w = acc[i][j + 3] + bias[c + 3];
      *reinterpret_cast<float4*>(&C[(size_t)r * ldc + c]) = o;
    }
  }
}

// ---------------------------------------------------------------------------
// Laplace features for q and k.  One wave = one (which,b,h) x TW_ tokens.
// lane -> feature index (r*32+m); omega column cached in 64 VGPRs.
// ---------------------------------------------------------------------------
__global__ __launch_bounds__(256) void features_k(
    const float* __restrict__ qkv, const float* __restrict__ omega,
    const float* __restrict__ qnodes, const float* __restrict__ qweights,
    float* __restrict__ qf, float* __restrict__ kf)
{
  const int wave = blockIdx.x * 4 + (threadIdx.x >> 6);
  const int lane = threadIdx.x & 63;
  const int ntg = T_ / TW_;  // 64
  int tmp = wave;
  const int tg = tmp % ntg; tmp /= ntg;
  const int h = tmp % HEADS_; tmp /= HEADS_;
  const int b = tmp % B_; tmp /= B_;
  const int which = tmp;  // 0 -> q, 1 -> k
  const int r = lane >> 5, m = lane & 31;

  float om[64];
#pragma unroll
  for (int d = 0; d < 64; ++d)
    om[d] = omega[(((size_t)r * HEADS_ + h) * HD_ + d) * M_ + m];

  const float s = qnodes[r];
  const float sq2s = sqrtf(2.f * fmaxf(s, 0.f));
  const float scale = sqrtf(fmaxf(qweights[r], 0.f)) * 0.17677669529663687f; // /sqrt(32)

  float* __restrict__ dst = which ? kf : qf;
  const size_t srcbase =
      ((size_t)b * T_) * (3 * EMBED_) + (size_t)which * EMBED_ + h * HD_;
  const size_t dstbase = ((size_t)(b * HEADS_ + h)) * T_ * FD_;

  for (int tt = 0; tt < TW_; ++tt) {
    const int t = tg * TW_ + tt;
    float val = qkv[srcbase + (size_t)t * (3 * EMBED_) + lane];
    float ss = val * val;
#pragma unroll
    for (int o = 32; o > 0; o >>= 1) ss += __shfl_xor(ss, o, 64);
    float xn = val / fmaxf(sqrtf(ss), 1e-12f);
    float proj = 0.f;
#pragma unroll
    for (int d = 0; d < 64; ++d) proj += __shfl(xn, d, 64) * om[d];
    float arg = proj * sq2s - s;
    arg = fminf(fmaxf(arg, -20.f), 20.f);
    dst[dstbase + (size_t)t * FD_ + lane] = expf(arg) * scale;
  }
}

// ---------------------------------------------------------------------------
// Per-chunk KV = kf^T @ v (64x64) and Ksum = sum_t kf  (one block per chunk)
// ---------------------------------------------------------------------------
__global__ __launch_bounds__(256) void chunk_sums_k(
    const float* __restrict__ kf, const float* __restrict__ qkv,
    float* __restrict__ kvsum, float* __restrict__ ksum)
{
  const int blk = blockIdx.x;  // bh*NCH + c
  const int c = blk % NCH;
  const int bh = blk / NCH;
  const int b = bh / HEADS_, h = bh % HEADS_;
  const int tid = threadIdx.x;
  const int d = tid & 63;
  const int fq = tid >> 6;  // 0..3
  __shared__ float kf_s[16][64];
  __shared__ float v_s[16][64];
  float acc[16];
#pragma unroll
  for (int i = 0; i < 16; ++i) acc[i] = 0.f;
  float ks = 0.f;
  for (int t0 = 0; t0 < LCH; t0 += 16) {
#pragma unroll
    for (int l = 0; l < 4; ++l) {
      int idx = tid + l * 256;
      int rr = idx >> 6, cc = idx & 63;
      int t = c * LCH + t0 + rr;
      kf_s[rr][cc] = kf[((size_t)bh * T_ + t) * FD_ + cc];
      v_s[rr][cc] =
          qkv[((size_t)(b * T_ + t)) * (3 * EMBED_) + 2 * EMBED_ + h * HD_ + cc];
    }
    __syncthreads();
#pragma unroll
    for (int tt = 0; tt < 16; ++tt) {
      float vv = v_s[tt][d];
      if (fq == 0) ks += kf_s[tt][d];
#pragma unroll
      for (int i = 0; i < 16; ++i) acc[i] += kf_s[tt][fq * 16 + i] * vv;
    }
    __syncthreads();
  }
#pragma unroll
  for (int i = 0; i < 16; ++i)
    kvsum[(size_t)blk * 4096 + (size_t)(fq * 16 + i) * 64 + d] = acc[i];
  if (fq == 0) ksum[(size_t)blk * 64 + d] = ks;
}

// ---------------------------------------------------------------------------
// Exclusive prefix over chunks (per bh), in place.
// ---------------------------------------------------------------------------
__global__ __launch_bounds__(256) void prefix_k(float* __restrict__ kvsum,
                                                float* __restrict__ ksum)
{
  const int bh = blockIdx.x;
  const int tid = threadIdx.x;
  for (int e = tid; e < 4096; e += 256) {
    float run = 0.f;
    for (int c = 0; c < NCH; ++c) {
      float* p = &kvsum[((size_t)(bh * NCH + c)) * 4096 + e];
      float cur = *p; *p = run; run += cur;
    }
  }
  if (tid < 64) {
    float run = 0.f;
    for (int c = 0; c < NCH; ++c) {
      float* p = &ksum[((size_t)(bh * NCH + c)) * 64 + tid];
      float cur = *p; *p = run; run += cur;
    }
  }
}

// ---------------------------------------------------------------------------
// Per-chunk causal attention output. One wave per (bh, chunk); lane = row t.
// out_t = (qf_t . S_prev  +  sum_{s<=t} (qf_t.kf_s) v_s) / max(den,1e-6)
// Written into the dead q-columns of qkv (row stride 3072).
// ---------------------------------------------------------------------------
__global__ __launch_bounds__(64) void chunk_attn_k(
    const float* __restrict__ qf, const float* __restrict__ kf,
    const float* qkv_v, const float* __restrict__ kvsum,
    const float* __restrict__ ksum, float* attn)
{
  const int blk = blockIdx.x;
  const int c = blk % NCH;
  const int bh = blk / NCH;
  const int b = bh / HEADS_, h = bh % HEADS_;
  const int lane = threadIdx.x;
  __shared__ float kf_s[64][64];
  __shared__ float v_s[64][64];
  __shared__ float S_s[64][64];
  __shared__ float qf_s[64][68];  // pad to 68 floats: 16B-aligned rows, bank-spread
  __shared__ float sv[64];
  for (int rr = 0; rr < 64; ++rr) {
    kf_s[rr][lane] = kf[((size_t)bh * T_ + c * LCH + rr) * FD_ + lane];
    v_s[rr][lane] = qkv_v[((size_t)(b * T_ + c * LCH + rr)) * (3 * EMBED_) +
                          2 * EMBED_ + h * HD_ + lane];
    S_s[rr][lane] = kvsum[(size_t)blk * 4096 + (size_t)rr * 64 + lane];
    qf_s[rr][lane] = qf[((size_t)bh * T_ + c * LCH + rr) * FD_ + lane];
  }
  sv[lane] = ksum[(size_t)blk * 64 + lane];
  __syncthreads();

  const int t = lane;
  float q_r[64];
#pragma unroll
  for (int d4 = 0; d4 < 16; ++d4)
    *reinterpret_cast<float4*>(&q_r[d4 * 4]) =
        *reinterpret_cast<const float4*>(&qf_s[t][d4 * 4]);

  float ctx[64];
#pragma unroll
  for (int d = 0; d < 64; ++d) ctx[d] = 0.f;
  float den = 0.f;

  // history part: ctx += qf . S_prev ; den += qf . s_prev
  for (int f4 = 0; f4 < 16; ++f4) {
    float4 qv4 = *reinterpret_cast<const float4*>(&qf_s[t][f4 * 4]);
    float qv[4] = {qv4.x, qv4.y, qv4.z, qv4.w};
#pragma unroll
    for (int j = 0; j < 4; ++j) {
      int f = f4 * 4 + j;
      den += qv[j] * sv[f];
#pragma unroll
      for (int d4 = 0; d4 < 16; ++d4) {
        float4 s4 = *reinterpret_cast<const float4*>(&S_s[f][d4 * 4]);
        ctx[d4 * 4 + 0] += qv[j] * s4.x;
        ctx[d4 * 4 + 1] += qv[j] * s4.y;
        ctx[d4 * 4 + 2] += qv[j] * s4.z;
        ctx[d4 * 4 + 3] += qv[j] * s4.w;
      }
    }
  }

  // intra-chunk causal (inclusive)
  for (int s = 0; s <= t; ++s) {
    float a = 0.f;
#pragma unroll
    for (int d4 = 0; d4 < 16; ++d4) {
      float4 k4 = *reinterpret_cast<const float4*>(&kf_s[s][d4 * 4]);
      a += q_r[d4 * 4 + 0] * k4.x + q_r[d4 * 4 + 1] * k4.y +
           q_r[d4 * 4 + 2] * k4.z + q_r[d4 * 4 + 3] * k4.w;
    }
    den += a;
#pragma unroll
    for (int d4 = 0; d4 < 16; ++d4) {
      float4 v4 = *reinterpret_cast<const float4*>(&v_s[s][d4 * 4]);
      ctx[d4 * 4 + 0] += a * v4.x;
      ctx[d4 * 4 + 1] += a * v4.y;
      ctx[d4 * 4 + 2] += a * v4.z;
      ctx[d4 * 4 + 3] += a * v4.w;
    }
  }

  den = fmaxf(den, 1e-6f);
  const float rden = 1.f / den;
  float* op = &attn[((size_t)(b * T_ + c * LCH + t)) * (3 * EMBED_) + h * HD_];
#pragma unroll
  for (int d4 = 0; d4 < 16; ++d4) {
    float4 o;
    o.x = ctx[d4 * 4 + 0] * rden;
    o.y = ctx[d4 * 4 + 1] * rden;
    o.z = ctx[d4 * 4 + 2] * rden;
    o.w = ctx[d4 * 4 + 3] * rden;
    *reinterpret_cast<float4*>(&op[d4 * 4]) = o;
  }
}

// ---------------------------------------------------------------------------
extern "C" void kernel_launch(void* const* d_in, const int* in_sizes, int n_in,
                              void* d_out, int out_size, void* d_ws,
                              size_t ws_size, hipStream_t stream)
{
  (void)in_sizes; (void)n_in; (void)out_size; (void)ws_size;
  const float* x = (const float*)d_in[0];
  const float* Wqkv = (const float*)d_in[1];
  const float* bqkv = (const float*)d_in[2];
  const float* Wout = (const float*)d_in[3];
  const float* bout = (const float*)d_in[4];
  const float* omega = (const float*)d_in[5];
  const float* qnodes = (const float*)d_in[6];
  const float* qweights = (const float*)d_in[7];
  float* out = (float*)d_out;

  float* ws = (float*)d_ws;
  float* qkv = ws;                                    // 4096*3072
  float* qf = qkv + (size_t)B_ * T_ * 3 * EMBED_;     // 32*2048*64
  float* kf = qf + (size_t)BH_ * T_ * FD_;            // 32*2048*64
  float* kvsum = kf + (size_t)BH_ * T_ * FD_;         // 32*32*4096
  float* ksum = kvsum + (size_t)BH_ * NCH * FD_ * HD_; // 32*32*64

  const int MT = B_ * T_;  // 4096

  // 1) qkv = x @ Wqkv + bqkv
  gemm_bias_k<<<dim3((3 * EMBED_) / 128, MT / 128), 256, 0, stream>>>(
      x, Wqkv, bqkv, qkv, MT, 3 * EMBED_, EMBED_, EMBED_, 3 * EMBED_,
      3 * EMBED_);
  // 2) Laplace features for q and k
  features_k<<<dim3(2 * B_ * HEADS_ * (T_ / TW_) / 4), 256, 0, stream>>>(
      qkv, omega, qnodes, qweights, qf, kf);
  // 3) per-chunk KV / Ksum
  chunk_sums_k<<<dim3(BH_ * NCH), 256, 0, stream>>>(kf, qkv, kvsum, ksum);
  // 4) exclusive prefix over chunks
  prefix_k<<<dim3(BH_), 256, 0, stream>>>(kvsum, ksum);
  // 5) per-chunk causal attention -> dead q-columns of qkv (stride 3072)
  chunk_attn_k<<<dim3(BH_ * NCH), 64, 0, stream>>>(qf, kf, qkv, kvsum, ksum,
                                                   qkv);
  // 6) out = attn @ Wout + bout
  gemm_bias_k<<<dim3(EMBED_ / 128, MT / 128), 256, 0, stream>>>(
      qkv, Wout, bout, out, MT, EMBED_, EMBED_, 3 * EMBED_, EMBED_, EMBED_);
}

// Round 2
// 491.550 us; speedup vs baseline: 1.6561x; 1.6561x over previous
//
#include <hip/hip_runtime.h>
#include <cstddef>
#include <cstdint>

#define B_ 2
#define T_ 2048
#define EMBED_ 1024
#define HEADS_ 16
#define HD_ 64
#define M_ 32
#define R_ 2
#define FD_ 64
#define LCH 64
#define NCH (T_ / LCH)  // 32
#define BH_ (B_ * HEADS_)
#define TW_ 32

typedef unsigned short u16;
using bf16x8 = __attribute__((ext_vector_type(8))) short;
using f32x4 = __attribute__((ext_vector_type(4))) float;

__device__ __forceinline__ u16 f2bf(float f) {
  uint32_t u = __float_as_uint(f);
  u += 0x7FFF + ((u >> 16) & 1);
  return (u16)(u >> 16);
}
__device__ __forceinline__ float bf2f(u16 h) {
  return __uint_as_float(((uint32_t)h) << 16);
}

__device__ __forceinline__ void gload_lds16(const void* g, void* l) {
  __builtin_amdgcn_global_load_lds(
      (const __attribute__((address_space(1))) unsigned int*)g,
      (__attribute__((address_space(3))) unsigned int*)l, 16, 0, 0);
}

// ---------------------------------------------------------------------------
// bf16 MFMA GEMM (m97 structure): C[M][ldc] = A[M][K]bf16 @ Bt[N][K]bf16^T + bias
// 128x128 tile, 4 waves, 4x4 frags of mfma_f32_16x16x32_bf16, BK=32,
// global_load_lds width-16 staging.
// ---------------------------------------------------------------------------
__global__ __launch_bounds__(256) void gemm_bf16_k(
    const u16* __restrict__ A, const u16* __restrict__ Bt,
    const float* __restrict__ bias, float* __restrict__ C, int K, int ldc)
{
  __shared__ u16 As[128 * 32];
  __shared__ u16 Bs[128 * 32];
  const int tid = threadIdx.x;
  const int row0 = blockIdx.y * 128, col0 = blockIdx.x * 128;
  const int lane = tid & 63;
  const int wr = tid >> 7, wc = (tid >> 6) & 1;  // 2x2 wave grid
  f32x4 acc[4][4];
#pragma unroll
  for (int m = 0; m < 4; ++m)
#pragma unroll
    for (int n = 0; n < 4; ++n)
#pragma unroll
      for (int r = 0; r < 4; ++r) acc[m][n][r] = 0.f;

  // staging slots: each 4KB inst covers 64 rows x 64B; thread -> (row, 16B col)
  const int srow = tid >> 2;            // 0..63
  const int skp = (tid & 3) * 8;        // ushort offset in row (0,8,16,24)
  const u16* Agp = A + (size_t)(row0 + srow) * K + skp;
  const u16* Bgp = Bt + (size_t)(col0 + srow) * K + skp;
  u16* AsW = As + (tid >> 6) * 512;     // wave-uniform LDS base
  u16* BsW = Bs + (tid >> 6) * 512;

  const int fr = lane & 15;
  const int fk = (lane >> 4) * 8;

  for (int k0 = 0; k0 < K; k0 += 32) {
    gload_lds16(Agp + k0, AsW);
    gload_lds16(Agp + k0 + (size_t)64 * K, AsW + 2048);
    gload_lds16(Bgp + k0, BsW);
    gload_lds16(Bgp + k0 + (size_t)64 * K, BsW + 2048);
    __syncthreads();
    bf16x8 a[4], b[4];
#pragma unroll
    for (int m = 0; m < 4; ++m)
      a[m] = *(const bf16x8*)&As[(wr * 64 + m * 16 + fr) * 32 + fk];
#pragma unroll
    for (int n = 0; n < 4; ++n)
      b[n] = *(const bf16x8*)&Bs[(wc * 64 + n * 16 + fr) * 32 + fk];
#pragma unroll
    for (int m = 0; m < 4; ++m)
#pragma unroll
      for (int n = 0; n < 4; ++n)
        acc[m][n] =
            __builtin_amdgcn_mfma_f32_16x16x32_bf16(a[m], b[n], acc[m][n], 0, 0, 0);
    __syncthreads();
  }
  const int fg = lane >> 4;
#pragma unroll
  for (int m = 0; m < 4; ++m) {
#pragma unroll
    for (int n = 0; n < 4; ++n) {
      const int col = col0 + wc * 64 + n * 16 + fr;
      const float bv = bias[col];
#pragma unroll
      for (int r = 0; r < 4; ++r) {
        const int row = row0 + wr * 64 + m * 16 + fg * 4 + r;
        C[(size_t)row * ldc + col] = acc[m][n][r] + bv;
      }
    }
  }
}

// ---------------------------------------------------------------------------
// split fp32 [M][1024] -> bf16 [M][3072] as [hi | lo | hi]
// ---------------------------------------------------------------------------
__global__ __launch_bounds__(256) void split_a_k(const float* __restrict__ X,
                                                 u16* __restrict__ Y, int Mrows)
{
  const int idx = blockIdx.x * 256 + threadIdx.x;  // float4 index
  if (idx >= Mrows * 256) return;
  const int r = idx >> 8, cq = idx & 255;
  float4 xv = *(const float4*)&X[(size_t)r * 1024 + cq * 4];
  float xs[4] = {xv.x, xv.y, xv.z, xv.w};
  ushort4 hi, lo;
  u16* hp = (u16*)&hi; u16* lp = (u16*)&lo;
#pragma unroll
  for (int j = 0; j < 4; ++j) {
    u16 h = f2bf(xs[j]);
    hp[j] = h;
    lp[j] = f2bf(xs[j] - bf2f(h));
  }
  const size_t base = (size_t)r * 3072 + cq * 4;
  *(ushort4*)&Y[base] = hi;
  *(ushort4*)&Y[base + 1024] = lo;
  *(ushort4*)&Y[base + 2048] = hi;
}

// ---------------------------------------------------------------------------
// split + transpose W [1024][N] fp32 -> Wt [N][3072] bf16 as [hi | hi | lo]
// ---------------------------------------------------------------------------
__global__ __launch_bounds__(256) void split_w_k(const float* __restrict__ W,
                                                 u16* __restrict__ Wt, int N)
{
  __shared__ float tile[32][33];
  const int n0 = blockIdx.x * 32, k0 = blockIdx.y * 32;
  const int tx = threadIdx.x & 31, ty = threadIdx.x >> 5;  // ty 0..7
#pragma unroll
  for (int i = 0; i < 4; ++i)
    tile[ty + i * 8][tx] = W[(size_t)(k0 + ty + i * 8) * N + n0 + tx];
  __syncthreads();
#pragma unroll
  for (int i = 0; i < 4; ++i) {
    const int n = ty + i * 8;
    const float x = tile[tx][n];
    const u16 h = f2bf(x);
    const u16 l = f2bf(x - bf2f(h));
    const size_t rowbase = (size_t)(n0 + n) * 3072 + k0 + tx;
    Wt[rowbase] = h;
    Wt[rowbase + 1024] = h;
    Wt[rowbase + 2048] = l;
  }
}

// ---------------------------------------------------------------------------
// fallback fp32 GEMM (round-1, proven)
// ---------------------------------------------------------------------------
__global__ __launch_bounds__(256) void gemm_bias_k(
    const float* __restrict__ A, const float* __restrict__ Bm,
    const float* __restrict__ bias, float* __restrict__ C,
    int Mdim, int Ndim, int Kdim, int lda, int ldb, int ldc)
{
  __shared__ float Asm[16][128];
  __shared__ float Bsm[16][128];
  const int tid = threadIdx.x;
  const int row0 = blockIdx.y * 128;
  const int col0 = blockIdx.x * 128;
  const int ty = tid >> 4, tx = tid & 15;
  float acc[8][8];
#pragma unroll
  for (int i = 0; i < 8; ++i)
#pragma unroll
    for (int j = 0; j < 8; ++j) acc[i][j] = 0.f;

  for (int k0 = 0; k0 < Kdim; k0 += 16) {
#pragma unroll
    for (int l = 0; l < 2; ++l) {
      int f = tid * 2 + l;
      int ar = f >> 2, aq = f & 3;
      float4 av = *reinterpret_cast<const float4*>(
          &A[(size_t)(row0 + ar) * lda + k0 + aq * 4]);
      Asm[aq * 4 + 0][ar] = av.x;
      Asm[aq * 4 + 1][ar] = av.y;
      Asm[aq * 4 + 2][ar] = av.z;
      Asm[aq * 4 + 3][ar] = av.w;
      int br = f >> 5, bc = f & 31;
      *reinterpret_cast<float4*>(&Bsm[br][bc * 4]) =
          *reinterpret_cast<const float4*>(
              &Bm[(size_t)(k0 + br) * ldb + col0 + bc * 4]);
    }
    __syncthreads();
#pragma unroll
    for (int kk = 0; kk < 16; ++kk) {
      float a[8], b[8];
      *reinterpret_cast<float4*>(&a[0]) =
          *reinterpret_cast<const float4*>(&Asm[kk][ty * 8]);
      *reinterpret_cast<float4*>(&a[4]) =
          *reinterpret_cast<const float4*>(&Asm[kk][ty * 8 + 4]);
      *reinterpret_cast<float4*>(&b[0]) =
          *reinterpret_cast<const float4*>(&Bsm[kk][tx * 8]);
      *reinterpret_cast<float4*>(&b[4]) =
          *reinterpret_cast<const float4*>(&Bsm[kk][tx * 8 + 4]);
#pragma unroll
      for (int i = 0; i < 8; ++i)
#pragma unroll
        for (int j = 0; j < 8; ++j) acc[i][j] += a[i] * b[j];
    }
    __syncthreads();
  }
#pragma unroll
  for (int i = 0; i < 8; ++i) {
    int r = row0 + ty * 8 + i;
#pragma unroll
    for (int j = 0; j < 8; j += 4) {
      int c = col0 + tx * 8 + j;
      float4 o;
      o.x = acc[i][j + 0] + bias[c + 0];
      o.y = acc[i][j + 1] + bias[c + 1];
      o.z = acc[i][j + 2] + bias[c + 2];
      o.w = acc[i][j + 3] + bias[c + 3];
      *reinterpret_cast<float4*>(&C[(size_t)r * ldc + c]) = o;
    }
  }
}

// ---------------------------------------------------------------------------
// Laplace features (unchanged from round 1)
// ---------------------------------------------------------------------------
__global__ __launch_bounds__(256) void features_k(
    const float* __restrict__ qkv, const float* __restrict__ omega,
    const float* __restrict__ qnodes, const float* __restrict__ qweights,
    float* __restrict__ qf, float* __restrict__ kf)
{
  const int wave = blockIdx.x * 4 + (threadIdx.x >> 6);
  const int lane = threadIdx.x & 63;
  const int ntg = T_ / TW_;
  int tmp = wave;
  const int tg = tmp % ntg; tmp /= ntg;
  const int h = tmp % HEADS_; tmp /= HEADS_;
  const int b = tmp % B_; tmp /= B_;
  const int which = tmp;
  const int r = lane >> 5, m = lane & 31;

  float om[64];
#pragma unroll
  for (int d = 0; d < 64; ++d)
    om[d] = omega[(((size_t)r * HEADS_ + h) * HD_ + d) * M_ + m];

  const float s = qnodes[r];
  const float sq2s = sqrtf(2.f * fmaxf(s, 0.f));
  const float scale = sqrtf(fmaxf(qweights[r], 0.f)) * 0.17677669529663687f;

  float* __restrict__ dst = which ? kf : qf;
  const size_t srcbase =
      ((size_t)b * T_) * (3 * EMBED_) + (size_t)which * EMBED_ + h * HD_;
  const size_t dstbase = ((size_t)(b * HEADS_ + h)) * T_ * FD_;

  for (int tt = 0; tt < TW_; ++tt) {
    const int t = tg * TW_ + tt;
    float val = qkv[srcbase + (size_t)t * (3 * EMBED_) + lane];
    float ss = val * val;
#pragma unroll
    for (int o = 32; o > 0; o >>= 1) ss += __shfl_xor(ss, o, 64);
    float xn = val / fmaxf(sqrtf(ss), 1e-12f);
    float proj = 0.f;
#pragma unroll
    for (int d = 0; d < 64; ++d) proj += __shfl(xn, d, 64) * om[d];
    float arg = proj * sq2s - s;
    arg = fminf(fmaxf(arg, -20.f), 20.f);
    dst[dstbase + (size_t)t * FD_ + lane] = expf(arg) * scale;
  }
}

// ---------------------------------------------------------------------------
// Per-chunk KV = kf^T @ v and Ksum (unchanged from round 1)
// ---------------------------------------------------------------------------
__global__ __launch_bounds__(256) void chunk_sums_k(
    const float* __restrict__ kf, const float* __restrict__ qkv,
    float* __restrict__ kvsum, float* __restrict__ ksum)
{
  const int blk = blockIdx.x;
  const int c = blk % NCH;
  const int bh = blk / NCH;
  const int b = bh / HEADS_, h = bh % HEADS_;
  const int tid = threadIdx.x;
  const int d = tid & 63;
  const int fq = tid >> 6;
  __shared__ float kf_s[16][64];
  __shared__ float v_s[16][64];
  float acc[16];
#pragma unroll
  for (int i = 0; i < 16; ++i) acc[i] = 0.f;
  float ks = 0.f;
  for (int t0 = 0; t0 < LCH; t0 += 16) {
#pragma unroll
    for (int l = 0; l < 4; ++l) {
      int idx = tid + l * 256;
      int rr = idx >> 6, cc = idx & 63;
      int t = c * LCH + t0 + rr;
      kf_s[rr][cc] = kf[((size_t)bh * T_ + t) * FD_ + cc];
      v_s[rr][cc] =
          qkv[((size_t)(b * T_ + t)) * (3 * EMBED_) + 2 * EMBED_ + h * HD_ + cc];
    }
    __syncthreads();
#pragma unroll
    for (int tt = 0; tt < 16; ++tt) {
      float vv = v_s[tt][d];
      if (fq == 0) ks += kf_s[tt][d];
#pragma unroll
      for (int i = 0; i < 16; ++i) acc[i] += kf_s[tt][fq * 16 + i] * vv;
    }
    __syncthreads();
  }
#pragma unroll
  for (int i = 0; i < 16; ++i)
    kvsum[(size_t)blk * 4096 + (size_t)(fq * 16 + i) * 64 + d] = acc[i];
  if (fq == 0) ksum[(size_t)blk * 64 + d] = ks;
}

// ---------------------------------------------------------------------------
// Exclusive prefix over chunks — register-resident, 512 blocks (latency fix)
// ---------------------------------------------------------------------------
__global__ __launch_bounds__(256) void prefix2_k(float* __restrict__ kvsum,
                                                 float* __restrict__ ksum)
{
  const int bh = blockIdx.x >> 4;
  const int eb = blockIdx.x & 15;
  const int e = eb * 256 + threadIdx.x;
  float v[NCH];
  const size_t base = (size_t)bh * NCH * 4096 + e;
#pragma unroll
  for (int c = 0; c < NCH; ++c) v[c] = kvsum[base + (size_t)c * 4096];
  float run = 0.f;
#pragma unroll
  for (int c = 0; c < NCH; ++c) {
    kvsum[base + (size_t)c * 4096] = run;
    run += v[c];
  }
  if (eb == 0 && threadIdx.x < 64) {
    const size_t kb = (size_t)bh * NCH * 64 + threadIdx.x;
    float w[NCH];
#pragma unroll
    for (int c = 0; c < NCH; ++c) w[c] = ksum[kb + c * 64];
    float r2 = 0.f;
#pragma unroll
    for (int c = 0; c < NCH; ++c) {
      ksum[kb + c * 64] = r2;
      r2 += w[c];
    }
  }
}

// ---------------------------------------------------------------------------
// Per-chunk causal attention, 4 waves/block.
// lane -> (t = w*16 + (l&15), d-quarter dq = l>>4); score reduced via shfl_xor.
// ---------------------------------------------------------------------------
__global__ __launch_bounds__(256) void chunk_attn2_k(
    const float* __restrict__ qf, const float* __restrict__ kf,
    const float* __restrict__ qkv_v, const float* __restrict__ kvsum,
    const float* __restrict__ ksum, float* __restrict__ attn, int lda)
{
  const int blk = blockIdx.x;
  const int c = blk & (NCH - 1);
  const int bh = blk / NCH;
  const int b = bh / HEADS_, h = bh % HEADS_;
  const int tid = threadIdx.x;
  __shared__ float kf_s[64][64];
  __shared__ float v_s[64][64];
  __shared__ float S_s[64][64];
  __shared__ float qf_s[64][64];
  {
    const int r = tid >> 2, q4 = (tid & 3) * 16;
    const size_t fbase = ((size_t)bh * T_ + c * LCH + r) * FD_ + q4;
    const size_t vbase =
        ((size_t)(b * T_ + c * LCH + r)) * (3 * EMBED_) + 2 * EMBED_ + h * HD_ + q4;
    const size_t sbase = (size_t)blk * 4096 + (size_t)r * 64 + q4;
#pragma unroll
    for (int j = 0; j < 16; j += 4) {
      *(float4*)&kf_s[r][q4 + j] = *(const float4*)&kf[fbase + j];
      *(float4*)&qf_s[r][q4 + j] = *(const float4*)&qf[fbase + j];
      *(float4*)&S_s[r][q4 + j] = *(const float4*)&kvsum[sbase + j];
      *(float4*)&v_s[r][q4 + j] = *(const float4*)&qkv_v[vbase + j];
    }
  }
  __syncthreads();
  const int l = tid & 63;
  const int t = (tid >> 6) * 16 + (l & 15);
  const int dq = l >> 4, d0 = dq * 16;

  float q_r[64];
#pragma unroll
  for (int j = 0; j < 64; j += 4)
    *(float4*)&q_r[j] = *(const float4*)&qf_s[t][j];

  float ctx[16];
#pragma unroll
  for (int j = 0; j < 16; ++j) ctx[j] = 0.f;
  float den = 0.f, den2 = 0.f;

  // history: ctx += qf . S_prev
#pragma unroll 4
  for (int f = 0; f < 64; ++f) {
    const float qv = q_r[f];
#pragma unroll
    for (int j = 0; j < 16; j += 4) {
      float4 s4 = *(const float4*)&S_s[f][d0 + j];
      ctx[j + 0] += qv * s4.x;
      ctx[j + 1] += qv * s4.y;
      ctx[j + 2] += qv * s4.z;
      ctx[j + 3] += qv * s4.w;
    }
  }
  // den partial (this lane's f-range) from global ksum (prefixed)
  {
    const float* svp = &ksum[(size_t)blk * 64 + d0];
#pragma unroll
    for (int j = 0; j < 16; ++j) den += q_r[d0 + j] * svp[j];
  }

  // intra-chunk causal
  for (int s = 0; s < LCH; ++s) {
    float a = 0.f;
#pragma unroll
    for (int j = 0; j < 16; j += 4) {
      float4 k4 = *(const float4*)&kf_s[s][d0 + j];
      a += q_r[d0 + j] * k4.x + q_r[d0 + j + 1] * k4.y +
           q_r[d0 + j + 2] * k4.z + q_r[d0 + j + 3] * k4.w;
    }
    a += __shfl_xor(a, 16, 64);
    a += __shfl_xor(a, 32, 64);
    if (s <= t) {
      den2 += a;
#pragma unroll
      for (int j = 0; j < 16; j += 4) {
        float4 v4 = *(const float4*)&v_s[s][d0 + j];
        ctx[j + 0] += a * v4.x;
        ctx[j + 1] += a * v4.y;
        ctx[j + 2] += a * v4.z;
        ctx[j + 3] += a * v4.w;
      }
    }
  }
  den += __shfl_xor(den, 16, 64);
  den += __shfl_xor(den, 32, 64);
  const float rden = 1.f / fmaxf(den + den2, 1e-6f);
  float* op = &attn[((size_t)(b * T_ + c * LCH + t)) * lda + h * HD_ + d0];
#pragma unroll
  for (int j = 0; j < 16; j += 4) {
    float4 o;
    o.x = ctx[j + 0] * rden;
    o.y = ctx[j + 1] * rden;
    o.z = ctx[j + 2] * rden;
    o.w = ctx[j + 3] * rden;
    *(float4*)&op[j] = o;
  }
}

// ---------------------------------------------------------------------------
extern "C" void kernel_launch(void* const* d_in, const int* in_sizes, int n_in,
                              void* d_out, int out_size, void* d_ws,
                              size_t ws_size, hipStream_t stream)
{
  (void)in_sizes; (void)n_in; (void)out_size;
  const float* x = (const float*)d_in[0];
  const float* Wqkv = (const float*)d_in[1];
  const float* bqkv = (const float*)d_in[2];
  const float* Wout = (const float*)d_in[3];
  const float* bout = (const float*)d_in[4];
  const float* omega = (const float*)d_in[5];
  const float* qnodes = (const float*)d_in[6];
  const float* qweights = (const float*)d_in[7];
  float* out = (float*)d_out;

  float* ws = (float*)d_ws;
  const size_t QKV_F = (size_t)B_ * T_ * 3 * EMBED_;   // 12,582,912
  const size_t F_F = (size_t)BH_ * T_ * FD_;           // 4,194,304
  const size_t KV_F = (size_t)BH_ * NCH * FD_ * HD_;   // 4,194,304
  const size_t KS_F = (size_t)BH_ * NCH * FD_;         // 65,536

  float* qkv = ws;
  float* qf = qkv + QKV_F;
  float* kf = qf + F_F;
  float* kvsum = kf + F_F;
  float* ksum = kvsum + KV_F;
  float* regionA = ksum + KS_F;                 // 6,291,456 floats
  float* regionW = regionA + QKV_F / 2;         // 4,718,592 floats
  const size_t needed = (size_t)(regionW + 3 * EMBED_ * EMBED_ * 3 / 2 - ws) * 4;

  const int MT = B_ * T_;

  if (ws_size >= needed) {
    u16* x_ext = (u16*)regionA;
    u16* wq_ext = (u16*)regionW;
    u16* wo_ext = (u16*)regionW;   // reused after gemm1
    float* attn = regionA;         // reused after gemm1 (x_ext dead)
    u16* attn_ext = (u16*)qkv;     // reused after chunk_attn (qkv dead)

    split_a_k<<<dim3(4096), 256, 0, stream>>>(x, x_ext, MT);
    split_w_k<<<dim3(96, 32), 256, 0, stream>>>(Wqkv, wq_ext, 3 * EMBED_);
    gemm_bf16_k<<<dim3(24, 32), 256, 0, stream>>>(x_ext, wq_ext, bqkv, qkv,
                                                  3072, 3 * EMBED_);
    features_k<<<dim3(1024), 256, 0, stream>>>(qkv, omega, qnodes, qweights,
                                               qf, kf);
    chunk_sums_k<<<dim3(BH_ * NCH), 256, 0, stream>>>(kf, qkv, kvsum, ksum);
    prefix2_k<<<dim3(512), 256, 0, stream>>>(kvsum, ksum);
    chunk_attn2_k<<<dim3(BH_ * NCH), 256, 0, stream>>>(qf, kf, qkv, kvsum,
                                                       ksum, attn, EMBED_);
    split_w_k<<<dim3(32, 32), 256, 0, stream>>>(Wout, wo_ext, EMBED_);
    split_a_k<<<dim3(4096), 256, 0, stream>>>(attn, attn_ext, MT);
    gemm_bf16_k<<<dim3(8, 32), 256, 0, stream>>>(attn_ext, wo_ext, bout, out,
                                                 3072, EMBED_);
  } else {
    // fallback: round-1 fp32 GEMM path (proven), with improved middle kernels
    gemm_bias_k<<<dim3(24, 32), 256, 0, stream>>>(
        x, Wqkv, bqkv, qkv, MT, 3 * EMBED_, EMBED_, EMBED_, 3 * EMBED_,
        3 * EMBED_);
    features_k<<<dim3(1024), 256, 0, stream>>>(qkv, omega, qnodes, qweights,
                                               qf, kf);
    chunk_sums_k<<<dim3(BH_ * NCH), 256, 0, stream>>>(kf, qkv, kvsum, ksum);
    prefix2_k<<<dim3(512), 256, 0, stream>>>(kvsum, ksum);
    chunk_attn2_k<<<dim3(BH_ * NCH), 256, 0, stream>>>(qf, kf, qkv, kvsum,
                                                       ksum, qkv, 3 * EMBED_);
    gemm_bias_k<<<dim3(8, 32), 256, 0, stream>>>(
        qkv, Wout, bout, out, MT, EMBED_, EMBED_, 3 * EMBED_, EMBED_, EMBED_);
  }
}

// Round 5
// 373.753 us; speedup vs baseline: 2.1780x; 1.3152x over previous
//
#include <hip/hip_runtime.h>
#include <cstddef>
#include <cstdint>

#define B_ 2
#define T_ 2048
#define EMBED_ 1024
#define HEADS_ 16
#define HD_ 64
#define M_ 32
#define R_ 2
#define FD_ 64
#define LCH 64
#define NCH (T_ / LCH)  // 32
#define BH_ (B_ * HEADS_)

typedef unsigned short u16;
using bf16x8 = __attribute__((ext_vector_type(8))) short;
using f32x4 = __attribute__((ext_vector_type(4))) float;

__device__ __forceinline__ u16 f2bf(float f) {
  uint32_t u = __float_as_uint(f);
  u += 0x7FFF + ((u >> 16) & 1);
  return (u16)(u >> 16);
}
__device__ __forceinline__ float bf2f(u16 h) {
  return __uint_as_float(((uint32_t)h) << 16);
}

__device__ __forceinline__ void gload_lds16(const void* g, void* l) {
  __builtin_amdgcn_global_load_lds(
      (const __attribute__((address_space(1))) unsigned int*)g,
      (__attribute__((address_space(3))) unsigned int*)l, 16, 0, 0);
}

// paired-row swizzle: LDS line L (128B) pos p (16B) holds global
// (row = 2L + (u>>2), slot = u&3) with u = p ^ (L&7).
// read offset (u16) for (tile row R, slot s):
__device__ __forceinline__ int swz_off(int R, int s) {
  return (R >> 1) * 64 + (((((R & 1) << 2) | s) ^ ((R >> 1) & 7)) * 8);
}

// ---------------------------------------------------------------------------
// bf16 MFMA GEMM, 128x128 tile, swizzled LDS (conflict-free ds_read_b128)
// C[M][ldc] = A[M][K] @ Bt[N][K]^T + bias
// ---------------------------------------------------------------------------
__global__ __launch_bounds__(256) void gemm_bf16_k(
    const u16* __restrict__ A, const u16* __restrict__ Bt,
    const float* __restrict__ bias, float* __restrict__ C, int K, int ldc)
{
  __shared__ u16 As[128 * 32];
  __shared__ u16 Bs[128 * 32];
  const int tid = threadIdx.x;
  const int row0 = blockIdx.y * 128, col0 = blockIdx.x * 128;
  const int lane = tid & 63;
  const int w = tid >> 6;
  const int wr = tid >> 7, wc = (tid >> 6) & 1;
  f32x4 acc[4][4];
#pragma unroll
  for (int m = 0; m < 4; ++m)
#pragma unroll
    for (int n = 0; n < 4; ++n)
#pragma unroll
      for (int r = 0; r < 4; ++r) acc[m][n][r] = 0.f;

  // staging: pre-swizzled per-lane global address, linear LDS dest
  const int u_ = (lane & 7) ^ (lane >> 3);
  const int srow = w * 16 + 2 * (lane >> 3) + (u_ >> 2);
  const int skp = (u_ & 3) * 8;
  const u16* Agp = A + (size_t)(row0 + srow) * K + skp;
  const u16* Bgp = Bt + (size_t)(col0 + srow) * K + skp;
  u16* AsW = As + w * 512;
  u16* BsW = Bs + w * 512;

  const int fr = lane & 15;
  const int s_ = lane >> 4;
  int aoff[4], boff[4];
#pragma unroll
  for (int m = 0; m < 4; ++m) aoff[m] = swz_off(wr * 64 + m * 16 + fr, s_);
#pragma unroll
  for (int n = 0; n < 4; ++n) boff[n] = swz_off(wc * 64 + n * 16 + fr, s_);

  for (int k0 = 0; k0 < K; k0 += 32) {
    gload_lds16(Agp + k0, AsW);
    gload_lds16(Agp + k0 + (size_t)64 * K, AsW + 2048);
    gload_lds16(Bgp + k0, BsW);
    gload_lds16(Bgp + k0 + (size_t)64 * K, BsW + 2048);
    __syncthreads();
    bf16x8 a[4], b[4];
#pragma unroll
    for (int m = 0; m < 4; ++m) a[m] = *(const bf16x8*)&As[aoff[m]];
#pragma unroll
    for (int n = 0; n < 4; ++n) b[n] = *(const bf16x8*)&Bs[boff[n]];
#pragma unroll
    for (int m = 0; m < 4; ++m)
#pragma unroll
      for (int n = 0; n < 4; ++n)
        acc[m][n] = __builtin_amdgcn_mfma_f32_16x16x32_bf16(a[m], b[n],
                                                            acc[m][n], 0, 0, 0);
    __syncthreads();
  }
  const int fg = lane >> 4;
#pragma unroll
  for (int m = 0; m < 4; ++m) {
#pragma unroll
    for (int n = 0; n < 4; ++n) {
      const int col = col0 + wc * 64 + n * 16 + fr;
      const float bv = bias[col];
#pragma unroll
      for (int r = 0; r < 4; ++r) {
        const int row = row0 + wr * 64 + m * 16 + fg * 4 + r;
        C[(size_t)row * ldc + col] = acc[m][n][r] + bv;
      }
    }
  }
}

// ---------------------------------------------------------------------------
// bf16 MFMA GEMM, 128x64 tile (for N=1024 output GEMM -> 512 blocks, 2/CU)
// ---------------------------------------------------------------------------
__global__ __launch_bounds__(256) void gemm_bf16_n64_k(
    const u16* __restrict__ A, const u16* __restrict__ Bt,
    const float* __restrict__ bias, float* __restrict__ C, int K, int ldc)
{
  __shared__ u16 As[128 * 32];
  __shared__ u16 Bs[64 * 32];
  const int tid = threadIdx.x;
  const int row0 = blockIdx.y * 128, col0 = blockIdx.x * 64;
  const int lane = tid & 63;
  const int w = tid >> 6;
  f32x4 acc[2][4];
#pragma unroll
  for (int m = 0; m < 2; ++m)
#pragma unroll
    for (int n = 0; n < 4; ++n)
#pragma unroll
      for (int r = 0; r < 4; ++r) acc[m][n][r] = 0.f;

  const int u_ = (lane & 7) ^ (lane >> 3);
  const int srow = w * 16 + 2 * (lane >> 3) + (u_ >> 2);
  const int skp = (u_ & 3) * 8;
  const u16* Agp = A + (size_t)(row0 + srow) * K + skp;
  const u16* Bgp = Bt + (size_t)(col0 + srow) * K + skp;
  u16* AsW = As + w * 512;
  u16* BsW = Bs + w * 512;

  const int fr = lane & 15;
  const int s_ = lane >> 4;
  int aoff[2], boff[4];
#pragma unroll
  for (int m = 0; m < 2; ++m) aoff[m] = swz_off(w * 32 + m * 16 + fr, s_);
#pragma unroll
  for (int n = 0; n < 4; ++n) boff[n] = swz_off(n * 16 + fr, s_);

  for (int k0 = 0; k0 < K; k0 += 32) {
    gload_lds16(Agp + k0, AsW);
    gload_lds16(Agp + k0 + (size_t)64 * K, AsW + 2048);
    gload_lds16(Bgp + k0, BsW);
    __syncthreads();
    bf16x8 a[2], b[4];
#pragma unroll
    for (int m = 0; m < 2; ++m) a[m] = *(const bf16x8*)&As[aoff[m]];
#pragma unroll
    for (int n = 0; n < 4; ++n) b[n] = *(const bf16x8*)&Bs[boff[n]];
#pragma unroll
    for (int m = 0; m < 2; ++m)
#pragma unroll
      for (int n = 0; n < 4; ++n)
        acc[m][n] = __builtin_amdgcn_mfma_f32_16x16x32_bf16(a[m], b[n],
                                                            acc[m][n], 0, 0, 0);
    __syncthreads();
  }
  const int fg = lane >> 4;
#pragma unroll
  for (int m = 0; m < 2; ++m) {
#pragma unroll
    for (int n = 0; n < 4; ++n) {
      const int col = col0 + n * 16 + fr;
      const float bv = bias[col];
#pragma unroll
      for (int r = 0; r < 4; ++r) {
        const int row = row0 + w * 32 + m * 16 + fg * 4 + r;
        C[(size_t)row * ldc + col] = acc[m][n][r] + bv;
      }
    }
  }
}

// ---------------------------------------------------------------------------
// split fp32 [M][1024] -> bf16 [M][3072] as [hi | lo | hi]
// ---------------------------------------------------------------------------
__global__ __launch_bounds__(256) void split_a_k(const float* __restrict__ X,
                                                 u16* __restrict__ Y, int Mrows)
{
  const int idx = blockIdx.x * 256 + threadIdx.x;
  if (idx >= Mrows * 256) return;
  const int r = idx >> 8, cq = idx & 255;
  float4 xv = *(const float4*)&X[(size_t)r * 1024 + cq * 4];
  float xs[4] = {xv.x, xv.y, xv.z, xv.w};
  ushort4 hi, lo;
  u16* hp = (u16*)&hi; u16* lp = (u16*)&lo;
#pragma unroll
  for (int j = 0; j < 4; ++j) {
    u16 h = f2bf(xs[j]);
    hp[j] = h;
    lp[j] = f2bf(xs[j] - bf2f(h));
  }
  const size_t base = (size_t)r * 3072 + cq * 4;
  *(ushort4*)&Y[base] = hi;
  *(ushort4*)&Y[base + 1024] = lo;
  *(ushort4*)&Y[base + 2048] = hi;
}

// ---------------------------------------------------------------------------
// split + transpose W [1024][N] fp32 -> Wt [N][3072] bf16 as [hi | hi | lo]
// ---------------------------------------------------------------------------
__global__ __launch_bounds__(256) void split_w_k(const float* __restrict__ W,
                                                 u16* __restrict__ Wt, int N)
{
  __shared__ float tile[32][33];
  const int n0 = blockIdx.x * 32, k0 = blockIdx.y * 32;
  const int tx = threadIdx.x & 31, ty = threadIdx.x >> 5;
#pragma unroll
  for (int i = 0; i < 4; ++i)
    tile[ty + i * 8][tx] = W[(size_t)(k0 + ty + i * 8) * N + n0 + tx];
  __syncthreads();
#pragma unroll
  for (int i = 0; i < 4; ++i) {
    const int n = ty + i * 8;
    const float x = tile[tx][n];
    const u16 h = f2bf(x);
    const u16 l = f2bf(x - bf2f(h));
    const size_t rowbase = (size_t)(n0 + n) * 3072 + k0 + tx;
    Wt[rowbase] = h;
    Wt[rowbase + 1024] = h;
    Wt[rowbase + 2048] = l;
  }
}

// ---------------------------------------------------------------------------
// fallback fp32 GEMM (round-1, proven)
// ---------------------------------------------------------------------------
__global__ __launch_bounds__(256) void gemm_bias_k(
    const float* __restrict__ A, const float* __restrict__ Bm,
    const float* __restrict__ bias, float* __restrict__ C,
    int Mdim, int Ndim, int Kdim, int lda, int ldb, int ldc)
{
  __shared__ float Asm[16][128];
  __shared__ float Bsm[16][128];
  const int tid = threadIdx.x;
  const int row0 = blockIdx.y * 128;
  const int col0 = blockIdx.x * 128;
  const int ty = tid >> 4, tx = tid & 15;
  float acc[8][8];
#pragma unroll
  for (int i = 0; i < 8; ++i)
#pragma unroll
    for (int j = 0; j < 8; ++j) acc[i][j] = 0.f;

  for (int k0 = 0; k0 < Kdim; k0 += 16) {
#pragma unroll
    for (int l = 0; l < 2; ++l) {
      int f = tid * 2 + l;
      int ar = f >> 2, aq = f & 3;
      float4 av = *reinterpret_cast<const float4*>(
          &A[(size_t)(row0 + ar) * lda + k0 + aq * 4]);
      Asm[aq * 4 + 0][ar] = av.x;
      Asm[aq * 4 + 1][ar] = av.y;
      Asm[aq * 4 + 2][ar] = av.z;
      Asm[aq * 4 + 3][ar] = av.w;
      int br = f >> 5, bc = f & 31;
      *reinterpret_cast<float4*>(&Bsm[br][bc * 4]) =
          *reinterpret_cast<const float4*>(
              &Bm[(size_t)(k0 + br) * ldb + col0 + bc * 4]);
    }
    __syncthreads();
#pragma unroll
    for (int kk = 0; kk < 16; ++kk) {
      float a[8], b[8];
      *reinterpret_cast<float4*>(&a[0]) =
          *reinterpret_cast<const float4*>(&Asm[kk][ty * 8]);
      *reinterpret_cast<float4*>(&a[4]) =
          *reinterpret_cast<const float4*>(&Asm[kk][ty * 8 + 4]);
      *reinterpret_cast<float4*>(&b[0]) =
          *reinterpret_cast<const float4*>(&Bsm[kk][tx * 8]);
      *reinterpret_cast<float4*>(&b[4]) =
          *reinterpret_cast<const float4*>(&Bsm[kk][tx * 8 + 4]);
#pragma unroll
      for (int i = 0; i < 8; ++i)
#pragma unroll
        for (int j = 0; j < 8; ++j) acc[i][j] += a[i] * b[j];
    }
    __syncthreads();
  }
#pragma unroll
  for (int i = 0; i < 8; ++i) {
    int r = row0 + ty * 8 + i;
#pragma unroll
    for (int j = 0; j < 8; j += 4) {
      int c = col0 + tx * 8 + j;
      float4 o;
      o.x = acc[i][j + 0] + bias[c + 0];
      o.y = acc[i][j + 1] + bias[c + 1];
      o.z = acc[i][j + 2] + bias[c + 2];
      o.w = acc[i][j + 3] + bias[c + 3];
      *reinterpret_cast<float4*>(&C[(size_t)r * ldc + c]) = o;
    }
  }
}

// ---------------------------------------------------------------------------
// Laplace features via MFMA: proj = (x @ omega) * (1/||x||), then exp/scale.
// Block = 64 tokens x 64 features for one (which,b,h). hi/lo split, K_ext=192.
// ---------------------------------------------------------------------------
__global__ __launch_bounds__(256) void features_mfma_k(
    const float* __restrict__ qkv, const float* __restrict__ omega,
    const float* __restrict__ qnodes, const float* __restrict__ qweights,
    float* __restrict__ qf, float* __restrict__ kf)
{
  __shared__ u16 Aext[64 * 200];
  __shared__ u16 Bext[64 * 200];
  __shared__ float rinv_s[64];
  const int tid = threadIdx.x;
  const int t0 = blockIdx.x * 64;
  const int h = blockIdx.y;
  const int b = blockIdx.z & 1;
  const int which = blockIdx.z >> 1;
  const int bh = b * HEADS_ + h;

  // ---- x tile: load 64x64 fp32, norm, hi/lo split into Aext [hi|lo|hi]
  {
    const int row = tid >> 2;
    const int seg = (tid & 3) * 16;
    const float* xsrc = &qkv[((size_t)(b * T_ + t0 + row)) * 3072 +
                             which * 1024 + h * 64 + seg];
    float xv[16];
#pragma unroll
    for (int q = 0; q < 4; ++q)
      *(float4*)&xv[q * 4] = *(const float4*)&xsrc[q * 4];
    float ss = 0.f;
#pragma unroll
    for (int j = 0; j < 16; ++j) ss += xv[j] * xv[j];
    ss += __shfl_xor(ss, 1, 64);
    ss += __shfl_xor(ss, 2, 64);
    if ((tid & 3) == 0) rinv_s[row] = 1.f / fmaxf(sqrtf(ss), 1e-12f);
    ushort4 hv[4], lv[4];
    u16* hp = (u16*)hv; u16* lp = (u16*)lv;
#pragma unroll
    for (int j = 0; j < 16; ++j) {
      u16 hh = f2bf(xv[j]);
      hp[j] = hh;
      lp[j] = f2bf(xv[j] - bf2f(hh));
    }
    u16* arow = &Aext[row * 200 + seg];
#pragma unroll
    for (int q = 0; q < 4; ++q) {
      *(ushort4*)&arow[q * 4] = hv[q];
      *(ushort4*)&arow[64 + q * 4] = lv[q];
      *(ushort4*)&arow[128 + q * 4] = hv[q];
    }
  }
  // ---- omega -> Bext [hi|hi|lo]; feature n = r*32+m, k = d
  {
    const int r_o = tid >> 7;
    const int dseg = (tid >> 5) & 3;
    const int m_o = tid & 31;
    const int n = r_o * 32 + m_o;
    const size_t obase =
        (((size_t)(r_o * HEADS_ + h)) * HD_ + dseg * 16) * M_ + m_o;
    ushort4 hv[4], lv[4];
    u16* hp = (u16*)hv; u16* lp = (u16*)lv;
#pragma unroll
    for (int i = 0; i < 16; ++i) {
      float v = omega[obase + (size_t)i * M_];
      u16 hh = f2bf(v);
      hp[i] = hh;
      lp[i] = f2bf(v - bf2f(hh));
    }
    u16* brow = &Bext[n * 200 + dseg * 16];
#pragma unroll
    for (int q = 0; q < 4; ++q) {
      *(ushort4*)&brow[q * 4] = hv[q];
      *(ushort4*)&brow[64 + q * 4] = hv[q];
      *(ushort4*)&brow[128 + q * 4] = lv[q];
    }
  }
  __syncthreads();

  const int lane = tid & 63;
  const int w = tid >> 6;
  const int fr = lane & 15, s_ = lane >> 4;
  f32x4 facc[4];
#pragma unroll
  for (int n = 0; n < 4; ++n)
#pragma unroll
    for (int r = 0; r < 4; ++r) facc[n][r] = 0.f;
  const u16* arow = &Aext[(w * 16 + fr) * 200 + s_ * 8];
#pragma unroll
  for (int kk = 0; kk < 6; ++kk) {
    bf16x8 av = *(const bf16x8*)&arow[kk * 32];
#pragma unroll
    for (int n = 0; n < 4; ++n) {
      bf16x8 bv = *(const bf16x8*)&Bext[(n * 16 + fr) * 200 + kk * 32 + s_ * 8];
      facc[n] = __builtin_amdgcn_mfma_f32_16x16x32_bf16(av, bv, facc[n], 0, 0, 0);
    }
  }

  const float s0 = qnodes[0], s1 = qnodes[1];
  const float sq0 = sqrtf(2.f * fmaxf(s0, 0.f));
  const float sq1 = sqrtf(2.f * fmaxf(s1, 0.f));
  const float sc0 = sqrtf(fmaxf(qweights[0], 0.f)) * 0.17677669529663687f;
  const float sc1 = sqrtf(fmaxf(qweights[1], 0.f)) * 0.17677669529663687f;
  float* __restrict__ dst = which ? kf : qf;
  const size_t base = ((size_t)bh * T_ + t0) * FD_;
  const int fg = lane >> 4;
#pragma unroll
  for (int n = 0; n < 4; ++n) {
    const int feat = n * 16 + fr;
    const int ridx = n >> 1;
    const float sq = ridx ? sq1 : sq0;
    const float so = ridx ? s1 : s0;
    const float sc = ridx ? sc1 : sc0;
#pragma unroll
    for (int j = 0; j < 4; ++j) {
      const int token = w * 16 + fg * 4 + j;
      const float pr = facc[n][j] * rinv_s[token];
      float arg = fminf(fmaxf(pr * sq - so, -20.f), 20.f);
      dst[base + (size_t)token * FD_ + feat] = expf(arg) * sc;
    }
  }
}

// ---------------------------------------------------------------------------
// Per-chunk KV = kf^T @ v and Ksum (unchanged)
// ---------------------------------------------------------------------------
__global__ __launch_bounds__(256) void chunk_sums_k(
    const float* __restrict__ kf, const float* __restrict__ qkv,
    float* __restrict__ kvsum, float* __restrict__ ksum)
{
  const int blk = blockIdx.x;
  const int c = blk % NCH;
  const int bh = blk / NCH;
  const int b = bh / HEADS_, h = bh % HEADS_;
  const int tid = threadIdx.x;
  const int d = tid & 63;
  const int fq = tid >> 6;
  __shared__ float kf_s[16][64];
  __shared__ float v_s[16][64];
  float acc[16];
#pragma unroll
  for (int i = 0; i < 16; ++i) acc[i] = 0.f;
  float ks = 0.f;
  for (int t0 = 0; t0 < LCH; t0 += 16) {
#pragma unroll
    for (int l = 0; l < 4; ++l) {
      int idx = tid + l * 256;
      int rr = idx >> 6, cc = idx & 63;
      int t = c * LCH + t0 + rr;
      kf_s[rr][cc] = kf[((size_t)bh * T_ + t) * FD_ + cc];
      v_s[rr][cc] =
          qkv[((size_t)(b * T_ + t)) * 3072 + 2 * EMBED_ + h * HD_ + cc];
    }
    __syncthreads();
#pragma unroll
    for (int tt = 0; tt < 16; ++tt) {
      float vv = v_s[tt][d];
      if (fq == 0) ks += kf_s[tt][d];
#pragma unroll
      for (int i = 0; i < 16; ++i) acc[i] += kf_s[tt][fq * 16 + i] * vv;
    }
    __syncthreads();
  }
#pragma unroll
  for (int i = 0; i < 16; ++i)
    kvsum[(size_t)blk * 4096 + (size_t)(fq * 16 + i) * 64 + d] = acc[i];
  if (fq == 0) ksum[(size_t)blk * 64 + d] = ks;
}

// ---------------------------------------------------------------------------
// Exclusive prefix over chunks — register-resident, 512 blocks
// ---------------------------------------------------------------------------
__global__ __launch_bounds__(256) void prefix2_k(float* __restrict__ kvsum,
                                                 float* __restrict__ ksum)
{
  const int bh = blockIdx.x >> 4;
  const int eb = blockIdx.x & 15;
  const int e = eb * 256 + threadIdx.x;
  float v[NCH];
  const size_t base = (size_t)bh * NCH * 4096 + e;
#pragma unroll
  for (int c = 0; c < NCH; ++c) v[c] = kvsum[base + (size_t)c * 4096];
  float run = 0.f;
#pragma unroll
  for (int c = 0; c < NCH; ++c) {
    kvsum[base + (size_t)c * 4096] = run;
    run += v[c];
  }
  if (eb == 0 && threadIdx.x < 64) {
    const size_t kb = (size_t)bh * NCH * 64 + threadIdx.x;
    float w[NCH];
#pragma unroll
    for (int c = 0; c < NCH; ++c) w[c] = ksum[kb + c * 64];
    float r2 = 0.f;
#pragma unroll
    for (int c = 0; c < NCH; ++c) {
      ksum[kb + c * 64] = r2;
      r2 += w[c];
    }
  }
}

// ---------------------------------------------------------------------------
// Per-chunk causal attention; optional fused bf16 [hi|lo|hi] ext output.
// ---------------------------------------------------------------------------
__global__ __launch_bounds__(256) void chunk_attn3_k(
    const float* __restrict__ qf, const float* __restrict__ kf,
    const float* __restrict__ qkv_v, const float* __restrict__ kvsum,
    const float* __restrict__ ksum, u16* __restrict__ out_ext,
    float* __restrict__ out_f32, int lda)
{
  const int blk = blockIdx.x;
  const int c = blk & (NCH - 1);
  const int bh = blk / NCH;
  const int b = bh / HEADS_, h = bh % HEADS_;
  const int tid = threadIdx.x;
  __shared__ float kf_s[64][64];
  __shared__ float v_s[64][64];
  __shared__ float S_s[64][64];
  __shared__ float qf_s[64][64];
  {
    const int r = tid >> 2, q4 = (tid & 3) * 16;
    const size_t fbase = ((size_t)bh * T_ + c * LCH + r) * FD_ + q4;
    const size_t vbase =
        ((size_t)(b * T_ + c * LCH + r)) * 3072 + 2 * EMBED_ + h * HD_ + q4;
    const size_t sbase = (size_t)blk * 4096 + (size_t)r * 64 + q4;
#pragma unroll
    for (int j = 0; j < 16; j += 4) {
      *(float4*)&kf_s[r][q4 + j] = *(const float4*)&kf[fbase + j];
      *(float4*)&qf_s[r][q4 + j] = *(const float4*)&qf[fbase + j];
      *(float4*)&S_s[r][q4 + j] = *(const float4*)&kvsum[sbase + j];
      *(float4*)&v_s[r][q4 + j] = *(const float4*)&qkv_v[vbase + j];
    }
  }
  __syncthreads();
  const int l = tid & 63;
  const int t = (tid >> 6) * 16 + (l & 15);
  const int dq = l >> 4, d0 = dq * 16;

  float q_r[64];
#pragma unroll
  for (int j = 0; j < 64; j += 4)
    *(float4*)&q_r[j] = *(const float4*)&qf_s[t][j];

  float ctx[16];
#pragma unroll
  for (int j = 0; j < 16; ++j) ctx[j] = 0.f;
  float den = 0.f, den2 = 0.f;

#pragma unroll 4
  for (int f = 0; f < 64; ++f) {
    const float qv = q_r[f];
#pragma unroll
    for (int j = 0; j < 16; j += 4) {
      float4 s4 = *(const float4*)&S_s[f][d0 + j];
      ctx[j + 0] += qv * s4.x;
      ctx[j + 1] += qv * s4.y;
      ctx[j + 2] += qv * s4.z;
      ctx[j + 3] += qv * s4.w;
    }
  }
  {
    const float* svp = &ksum[(size_t)blk * 64 + d0];
#pragma unroll
    for (int j = 0; j < 16; ++j) den += q_r[d0 + j] * svp[j];
  }

  for (int s = 0; s < LCH; ++s) {
    float a = 0.f;
#pragma unroll
    for (int j = 0; j < 16; j += 4) {
      float4 k4 = *(const float4*)&kf_s[s][d0 + j];
      a += q_r[d0 + j] * k4.x + q_r[d0 + j + 1] * k4.y +
           q_r[d0 + j + 2] * k4.z + q_r[d0 + j + 3] * k4.w;
    }
    a += __shfl_xor(a, 16, 64);
    a += __shfl_xor(a, 32, 64);
    if (s <= t) {
      den2 += a;
#pragma unroll
      for (int j = 0; j < 16; j += 4) {
        float4 v4 = *(const float4*)&v_s[s][d0 + j];
        ctx[j + 0] += a * v4.x;
        ctx[j + 1] += a * v4.y;
        ctx[j + 2] += a * v4.z;
        ctx[j + 3] += a * v4.w;
      }
    }
  }
  den += __shfl_xor(den, 16, 64);
  den += __shfl_xor(den, 32, 64);
  const float rden = 1.f / fmaxf(den + den2, 1e-6f);

  if (out_ext) {
    ushort4 hv[4], lv[4];
    u16* hp = (u16*)hv; u16* lp = (u16*)lv;
#pragma unroll
    for (int j = 0; j < 16; ++j) {
      float val = ctx[j] * rden;
      u16 hh = f2bf(val);
      hp[j] = hh;
      lp[j] = f2bf(val - bf2f(hh));
    }
    const size_t be = ((size_t)(b * T_ + c * LCH + t)) * 3072 + h * HD_ + d0;
#pragma unroll
    for (int q = 0; q < 4; ++q) {
      *(ushort4*)&out_ext[be + q * 4] = hv[q];
      *(ushort4*)&out_ext[be + 1024 + q * 4] = lv[q];
      *(ushort4*)&out_ext[be + 2048 + q * 4] = hv[q];
    }
  } else {
    float* op =
        &out_f32[((size_t)(b * T_ + c * LCH + t)) * lda + h * HD_ + d0];
#pragma unroll
    for (int j = 0; j < 16; j += 4) {
      float4 o;
      o.x = ctx[j + 0] * rden;
      o.y = ctx[j + 1] * rden;
      o.z = ctx[j + 2] * rden;
      o.w = ctx[j + 3] * rden;
      *(float4*)&op[j] = o;
    }
  }
}

// ---------------------------------------------------------------------------
extern "C" void kernel_launch(void* const* d_in, const int* in_sizes, int n_in,
                              void* d_out, int out_size, void* d_ws,
                              size_t ws_size, hipStream_t stream)
{
  (void)in_sizes; (void)n_in; (void)out_size;
  const float* x = (const float*)d_in[0];
  const float* Wqkv = (const float*)d_in[1];
  const float* bqkv = (const float*)d_in[2];
  const float* Wout = (const float*)d_in[3];
  const float* bout = (const float*)d_in[4];
  const float* omega = (const float*)d_in[5];
  const float* qnodes = (const float*)d_in[6];
  const float* qweights = (const float*)d_in[7];
  float* out = (float*)d_out;

  float* ws = (float*)d_ws;
  const size_t QKV_F = (size_t)B_ * T_ * 3 * EMBED_;
  const size_t F_F = (size_t)BH_ * T_ * FD_;
  const size_t KV_F = (size_t)BH_ * NCH * FD_ * HD_;
  const size_t KS_F = (size_t)BH_ * NCH * FD_;

  float* qkv = ws;
  float* qf = qkv + QKV_F;
  float* kf = qf + F_F;
  float* kvsum = kf + F_F;
  float* ksum = kvsum + KV_F;
  float* regionA = ksum + KS_F;          // x_ext, later attn_ext (u16)
  float* regionW = regionA + QKV_F / 2;  // wq_ext / wo_ext (u16)
  const size_t needed = (size_t)(regionW + 3 * EMBED_ * EMBED_ * 3 / 2 - ws) * 4;

  const int MT = B_ * T_;

  if (ws_size >= needed) {
    u16* x_ext = (u16*)regionA;
    u16* wq_ext = (u16*)regionW;
    u16* wo_ext = (u16*)regionW;
    u16* attn_ext = (u16*)regionA;  // reuse after gemm1 (x_ext dead)

    split_a_k<<<dim3(4096), 256, 0, stream>>>(x, x_ext, MT);
    split_w_k<<<dim3(96, 32), 256, 0, stream>>>(Wqkv, wq_ext, 3 * EMBED_);
    gemm_bf16_k<<<dim3(24, 32), 256, 0, stream>>>(x_ext, wq_ext, bqkv, qkv,
                                                  3072, 3 * EMBED_);
    features_mfma_k<<<dim3(T_ / 64, HEADS_, 4), 256, 0, stream>>>(
        qkv, omega, qnodes, qweights, qf, kf);
    chunk_sums_k<<<dim3(BH_ * NCH), 256, 0, stream>>>(kf, qkv, kvsum, ksum);
    prefix2_k<<<dim3(512), 256, 0, stream>>>(kvsum, ksum);
    split_w_k<<<dim3(32, 32), 256, 0, stream>>>(Wout, wo_ext, EMBED_);
    chunk_attn3_k<<<dim3(BH_ * NCH), 256, 0, stream>>>(
        qf, kf, qkv, kvsum, ksum, attn_ext, nullptr, 0);
    gemm_bf16_n64_k<<<dim3(16, 32), 256, 0, stream>>>(attn_ext, wo_ext, bout,
                                                      out, 3072, EMBED_);
  } else {
    gemm_bias_k<<<dim3(24, 32), 256, 0, stream>>>(
        x, Wqkv, bqkv, qkv, MT, 3 * EMBED_, EMBED_, EMBED_, 3 * EMBED_,
        3 * EMBED_);
    features_mfma_k<<<dim3(T_ / 64, HEADS_, 4), 256, 0, stream>>>(
        qkv, omega, qnodes, qweights, qf, kf);
    chunk_sums_k<<<dim3(BH_ * NCH), 256, 0, stream>>>(kf, qkv, kvsum, ksum);
    prefix2_k<<<dim3(512), 256, 0, stream>>>(kvsum, ksum);
    chunk_attn3_k<<<dim3(BH_ * NCH), 256, 0, stream>>>(
        qf, kf, qkv, kvsum, ksum, nullptr, qkv, 3 * EMBED_);
    gemm_bias_k<<<dim3(8, 32), 256, 0, stream>>>(
        qkv, Wout, bout, out, MT, EMBED_, EMBED_, 3 * EMBED_, EMBED_, EMBED_);
  }
}

// Round 10
// 271.765 us; speedup vs baseline: 2.9954x; 1.3753x over previous
//
#include <hip/hip_runtime.h>
#include <cstddef>
#include <cstdint>

#define B_ 2
#define T_ 2048
#define EMBED_ 1024
#define HEADS_ 16
#define HD_ 64
#define M_ 32
#define R_ 2
#define FD_ 64
#define LCH 64
#define NCH (T_ / LCH)  // 32
#define BH_ (B_ * HEADS_)

typedef unsigned short u16;
using bf16x8 = __attribute__((ext_vector_type(8))) short;
using f16x8 = __attribute__((ext_vector_type(8))) _Float16;
using f32x4 = __attribute__((ext_vector_type(4))) float;

__device__ __forceinline__ u16 f2bf(float f) {
  uint32_t u = __float_as_uint(f);
  u += 0x7FFF + ((u >> 16) & 1);
  return (u16)(u >> 16);
}
__device__ __forceinline__ float bf2f(u16 h) {
  return __uint_as_float(((uint32_t)h) << 16);
}
__device__ __forceinline__ u16 f2h(float f) {
  _Float16 h = (_Float16)f;
  return *(u16*)&h;
}

__device__ __forceinline__ void gload_lds16(const void* g, void* l) {
  __builtin_amdgcn_global_load_lds(
      (const __attribute__((address_space(1))) unsigned int*)g,
      (__attribute__((address_space(3))) unsigned int*)l, 16, 0, 0);
}

// paired-row swizzle (round-5 proven: SQ_LDS_BANK_CONFLICT == 0)
__device__ __forceinline__ int swz_off(int R, int s) {
  return (R >> 1) * 64 + (((((R & 1) << 2) | s) ^ ((R >> 1) & 7)) * 8);
}

// ---------------------------------------------------------------------------
// fp16 MFMA GEMM, 128x128 tile, swizzled LDS, double-buffered counted overlap
// (T3-min): stage next K-tile before compute, one barrier per K-step.
// C[M][ldc] = A[M][K]f16 @ Bt[N][K]f16^T + bias
// ---------------------------------------------------------------------------
__global__ __launch_bounds__(256) void gemm_f16_k(
    const u16* __restrict__ A, const u16* __restrict__ Bt,
    const float* __restrict__ bias, float* __restrict__ C, int K, int ldc)
{
  __shared__ u16 As[2][128 * 32];
  __shared__ u16 Bs[2][128 * 32];
  const int tid = threadIdx.x;
  const int row0 = blockIdx.y * 128, col0 = blockIdx.x * 128;
  const int lane = tid & 63;
  const int w = tid >> 6;
  const int wr = tid >> 7, wc = (tid >> 6) & 1;
  f32x4 acc[4][4];
#pragma unroll
  for (int m = 0; m < 4; ++m)
#pragma unroll
    for (int n = 0; n < 4; ++n)
#pragma unroll
      for (int r = 0; r < 4; ++r) acc[m][n][r] = 0.f;

  // staging: pre-swizzled per-lane global address, linear LDS dest
  const int u_ = (lane & 7) ^ (lane >> 3);
  const int srow = w * 16 + 2 * (lane >> 3) + (u_ >> 2);
  const int skp = (u_ & 3) * 8;
  const u16* Agp = A + (size_t)(row0 + srow) * K + skp;
  const u16* Bgp = Bt + (size_t)(col0 + srow) * K + skp;
  const int wb = w * 512;

  const int fr = lane & 15;
  const int s_ = lane >> 4;
  int aoff[4], boff[4];
#pragma unroll
  for (int m = 0; m < 4; ++m) aoff[m] = swz_off(wr * 64 + m * 16 + fr, s_);
#pragma unroll
  for (int n = 0; n < 4; ++n) boff[n] = swz_off(wc * 64 + n * 16 + fr, s_);

  const int nt = K >> 5;
  // prologue: stage tile 0
  gload_lds16(Agp, &As[0][wb]);
  gload_lds16(Agp + (size_t)64 * K, &As[0][wb + 2048]);
  gload_lds16(Bgp, &Bs[0][wb]);
  gload_lds16(Bgp + (size_t)64 * K, &Bs[0][wb + 2048]);
  __syncthreads();

  for (int t = 0; t < nt; ++t) {
    const int cur = t & 1;
    if (t + 1 < nt) {  // issue next-tile loads; drained by the barrier below
      const int k0 = (t + 1) * 32;
      gload_lds16(Agp + k0, &As[cur ^ 1][wb]);
      gload_lds16(Agp + k0 + (size_t)64 * K, &As[cur ^ 1][wb + 2048]);
      gload_lds16(Bgp + k0, &Bs[cur ^ 1][wb]);
      gload_lds16(Bgp + k0 + (size_t)64 * K, &Bs[cur ^ 1][wb + 2048]);
    }
    f16x8 a[4], b[4];
#pragma unroll
    for (int m = 0; m < 4; ++m) a[m] = *(const f16x8*)&As[cur][aoff[m]];
#pragma unroll
    for (int n = 0; n < 4; ++n) b[n] = *(const f16x8*)&Bs[cur][boff[n]];
#pragma unroll
    for (int m = 0; m < 4; ++m)
#pragma unroll
      for (int n = 0; n < 4; ++n)
        acc[m][n] = __builtin_amdgcn_mfma_f32_16x16x32_f16(a[m], b[n],
                                                           acc[m][n], 0, 0, 0);
    __syncthreads();  // drains vmcnt(0): next tile ready; cur safe to reuse
  }
  const int fg = lane >> 4;
#pragma unroll
  for (int m = 0; m < 4; ++m) {
#pragma unroll
    for (int n = 0; n < 4; ++n) {
      const int col = col0 + wc * 64 + n * 16 + fr;
      const float bv = bias[col];
#pragma unroll
      for (int r = 0; r < 4; ++r) {
        const int row = row0 + wr * 64 + m * 16 + fg * 4 + r;
        C[(size_t)row * ldc + col] = acc[m][n][r] + bv;
      }
    }
  }
}

// ---------------------------------------------------------------------------
// fp16 MFMA GEMM, 128x64 tile, dbuf (N=1024 output GEMM -> 512 blocks)
// ---------------------------------------------------------------------------
__global__ __launch_bounds__(256) void gemm_f16_n64_k(
    const u16* __restrict__ A, const u16* __restrict__ Bt,
    const float* __restrict__ bias, float* __restrict__ C, int K, int ldc)
{
  __shared__ u16 As[2][128 * 32];
  __shared__ u16 Bs[2][64 * 32];
  const int tid = threadIdx.x;
  const int row0 = blockIdx.y * 128, col0 = blockIdx.x * 64;
  const int lane = tid & 63;
  const int w = tid >> 6;
  f32x4 acc[2][4];
#pragma unroll
  for (int m = 0; m < 2; ++m)
#pragma unroll
    for (int n = 0; n < 4; ++n)
#pragma unroll
      for (int r = 0; r < 4; ++r) acc[m][n][r] = 0.f;

  const int u_ = (lane & 7) ^ (lane >> 3);
  const int srow = w * 16 + 2 * (lane >> 3) + (u_ >> 2);
  const int skp = (u_ & 3) * 8;
  const u16* Agp = A + (size_t)(row0 + srow) * K + skp;
  const u16* Bgp = Bt + (size_t)(col0 + srow) * K + skp;
  const int wb = w * 512;

  const int fr = lane & 15;
  const int s_ = lane >> 4;
  int aoff[2], boff[4];
#pragma unroll
  for (int m = 0; m < 2; ++m) aoff[m] = swz_off(w * 32 + m * 16 + fr, s_);
#pragma unroll
  for (int n = 0; n < 4; ++n) boff[n] = swz_off(n * 16 + fr, s_);

  const int nt = K >> 5;
  gload_lds16(Agp, &As[0][wb]);
  gload_lds16(Agp + (size_t)64 * K, &As[0][wb + 2048]);
  gload_lds16(Bgp, &Bs[0][wb]);
  __syncthreads();

  for (int t = 0; t < nt; ++t) {
    const int cur = t & 1;
    if (t + 1 < nt) {
      const int k0 = (t + 1) * 32;
      gload_lds16(Agp + k0, &As[cur ^ 1][wb]);
      gload_lds16(Agp + k0 + (size_t)64 * K, &As[cur ^ 1][wb + 2048]);
      gload_lds16(Bgp + k0, &Bs[cur ^ 1][wb]);
    }
    f16x8 a[2], b[4];
#pragma unroll
    for (int m = 0; m < 2; ++m) a[m] = *(const f16x8*)&As[cur][aoff[m]];
#pragma unroll
    for (int n = 0; n < 4; ++n) b[n] = *(const f16x8*)&Bs[cur][boff[n]];
#pragma unroll
    for (int m = 0; m < 2; ++m)
#pragma unroll
      for (int n = 0; n < 4; ++n)
        acc[m][n] = __builtin_amdgcn_mfma_f32_16x16x32_f16(a[m], b[n],
                                                           acc[m][n], 0, 0, 0);
    __syncthreads();
  }
  const int fg = lane >> 4;
#pragma unroll
  for (int m = 0; m < 2; ++m) {
#pragma unroll
    for (int n = 0; n < 4; ++n) {
      const int col = col0 + n * 16 + fr;
      const float bv = bias[col];
#pragma unroll
      for (int r = 0; r < 4; ++r) {
        const int row = row0 + w * 32 + m * 16 + fg * 4 + r;
        C[(size_t)row * ldc + col] = acc[m][n][r] + bv;
      }
    }
  }
}

// ---------------------------------------------------------------------------
// fp32 -> fp16 elementwise convert (8 elems/thread)
// ---------------------------------------------------------------------------
__global__ __launch_bounds__(256) void cvt_x_f16_k(const float* __restrict__ X,
                                                   u16* __restrict__ Y, int n8)
{
  const int idx = blockIdx.x * 256 + threadIdx.x;
  if (idx >= n8) return;
  float4 a = *(const float4*)&X[(size_t)idx * 8];
  float4 b = *(const float4*)&X[(size_t)idx * 8 + 4];
  ushort4 o0, o1;
  o0.x = f2h(a.x); o0.y = f2h(a.y); o0.z = f2h(a.z); o0.w = f2h(a.w);
  o1.x = f2h(b.x); o1.y = f2h(b.y); o1.z = f2h(b.z); o1.w = f2h(b.w);
  *(ushort4*)&Y[(size_t)idx * 8] = o0;
  *(ushort4*)&Y[(size_t)idx * 8 + 4] = o1;
}

// ---------------------------------------------------------------------------
// transpose + convert W [1024][N] fp32 -> Wt [N][1024] fp16
// ---------------------------------------------------------------------------
__global__ __launch_bounds__(256) void cvt_w_f16t_k(const float* __restrict__ W,
                                                    u16* __restrict__ Wt, int N)
{
  __shared__ float tile[32][33];
  const int n0 = blockIdx.x * 32, k0 = blockIdx.y * 32;
  const int tx = threadIdx.x & 31, ty = threadIdx.x >> 5;
#pragma unroll
  for (int i = 0; i < 4; ++i)
    tile[ty + i * 8][tx] = W[(size_t)(k0 + ty + i * 8) * N + n0 + tx];
  __syncthreads();
#pragma unroll
  for (int i = 0; i < 4; ++i) {
    const int n = ty + i * 8;
    Wt[(size_t)(n0 + n) * 1024 + k0 + tx] = f2h(tile[tx][n]);
  }
}

// ---------------------------------------------------------------------------
// fallback fp32 GEMM (round-1, proven)
// ---------------------------------------------------------------------------
__global__ __launch_bounds__(256) void gemm_bias_k(
    const float* __restrict__ A, const float* __restrict__ Bm,
    const float* __restrict__ bias, float* __restrict__ C,
    int Mdim, int Ndim, int Kdim, int lda, int ldb, int ldc)
{
  __shared__ float Asm[16][128];
  __shared__ float Bsm[16][128];
  const int tid = threadIdx.x;
  const int row0 = blockIdx.y * 128;
  const int col0 = blockIdx.x * 128;
  const int ty = tid >> 4, tx = tid & 15;
  float acc[8][8];
#pragma unroll
  for (int i = 0; i < 8; ++i)
#pragma unroll
    for (int j = 0; j < 8; ++j) acc[i][j] = 0.f;

  for (int k0 = 0; k0 < Kdim; k0 += 16) {
#pragma unroll
    for (int l = 0; l < 2; ++l) {
      int f = tid * 2 + l;
      int ar = f >> 2, aq = f & 3;
      float4 av = *reinterpret_cast<const float4*>(
          &A[(size_t)(row0 + ar) * lda + k0 + aq * 4]);
      Asm[aq * 4 + 0][ar] = av.x;
      Asm[aq * 4 + 1][ar] = av.y;
      Asm[aq * 4 + 2][ar] = av.z;
      Asm[aq * 4 + 3][ar] = av.w;
      int br = f >> 5, bc = f & 31;
      *reinterpret_cast<float4*>(&Bsm[br][bc * 4]) =
          *reinterpret_cast<const float4*>(
              &Bm[(size_t)(k0 + br) * ldb + col0 + bc * 4]);
    }
    __syncthreads();
#pragma unroll
    for (int kk = 0; kk < 16; ++kk) {
      float a[8], b[8];
      *reinterpret_cast<float4*>(&a[0]) =
          *reinterpret_cast<const float4*>(&Asm[kk][ty * 8]);
      *reinterpret_cast<float4*>(&a[4]) =
          *reinterpret_cast<const float4*>(&Asm[kk][ty * 8 + 4]);
      *reinterpret_cast<float4*>(&b[0]) =
          *reinterpret_cast<const float4*>(&Bsm[kk][tx * 8]);
      *reinterpret_cast<float4*>(&b[4]) =
          *reinterpret_cast<const float4*>(&Bsm[kk][tx * 8 + 4]);
#pragma unroll
      for (int i = 0; i < 8; ++i)
#pragma unroll
        for (int j = 0; j < 8; ++j) acc[i][j] += a[i] * b[j];
    }
    __syncthreads();
  }
#pragma unroll
  for (int i = 0; i < 8; ++i) {
    int r = row0 + ty * 8 + i;
#pragma unroll
    for (int j = 0; j < 8; j += 4) {
      int c = col0 + tx * 8 + j;
      float4 o;
      o.x = acc[i][j + 0] + bias[c + 0];
      o.y = acc[i][j + 1] + bias[c + 1];
      o.z = acc[i][j + 2] + bias[c + 2];
      o.w = acc[i][j + 3] + bias[c + 3];
      *reinterpret_cast<float4*>(&C[(size_t)r * ldc + c]) = o;
    }
  }
}

// ---------------------------------------------------------------------------
// Laplace features via MFMA (bf16 hi/lo, K_ext=192) — unchanged from round 5
// ---------------------------------------------------------------------------
__global__ __launch_bounds__(256) void features_mfma_k(
    const float* __restrict__ qkv, const float* __restrict__ omega,
    const float* __restrict__ qnodes, const float* __restrict__ qweights,
    float* __restrict__ qf, float* __restrict__ kf)
{
  __shared__ u16 Aext[64 * 200];
  __shared__ u16 Bext[64 * 200];
  __shared__ float rinv_s[64];
  const int tid = threadIdx.x;
  const int t0 = blockIdx.x * 64;
  const int h = blockIdx.y;
  const int b = blockIdx.z & 1;
  const int which = blockIdx.z >> 1;
  const int bh = b * HEADS_ + h;

  {
    const int row = tid >> 2;
    const int seg = (tid & 3) * 16;
    const float* xsrc = &qkv[((size_t)(b * T_ + t0 + row)) * 3072 +
                             which * 1024 + h * 64 + seg];
    float xv[16];
#pragma unroll
    for (int q = 0; q < 4; ++q)
      *(float4*)&xv[q * 4] = *(const float4*)&xsrc[q * 4];
    float ss = 0.f;
#pragma unroll
    for (int j = 0; j < 16; ++j) ss += xv[j] * xv[j];
    ss += __shfl_xor(ss, 1, 64);
    ss += __shfl_xor(ss, 2, 64);
    if ((tid & 3) == 0) rinv_s[row] = 1.f / fmaxf(sqrtf(ss), 1e-12f);
    ushort4 hv[4], lv[4];
    u16* hp = (u16*)hv; u16* lp = (u16*)lv;
#pragma unroll
    for (int j = 0; j < 16; ++j) {
      u16 hh = f2bf(xv[j]);
      hp[j] = hh;
      lp[j] = f2bf(xv[j] - bf2f(hh));
    }
    u16* arow = &Aext[row * 200 + seg];
#pragma unroll
    for (int q = 0; q < 4; ++q) {
      *(ushort4*)&arow[q * 4] = hv[q];
      *(ushort4*)&arow[64 + q * 4] = lv[q];
      *(ushort4*)&arow[128 + q * 4] = hv[q];
    }
  }
  {
    const int r_o = tid >> 7;
    const int dseg = (tid >> 5) & 3;
    const int m_o = tid & 31;
    const int n = r_o * 32 + m_o;
    const size_t obase =
        (((size_t)(r_o * HEADS_ + h)) * HD_ + dseg * 16) * M_ + m_o;
    ushort4 hv[4], lv[4];
    u16* hp = (u16*)hv; u16* lp = (u16*)lv;
#pragma unroll
    for (int i = 0; i < 16; ++i) {
      float v = omega[obase + (size_t)i * M_];
      u16 hh = f2bf(v);
      hp[i] = hh;
      lp[i] = f2bf(v - bf2f(hh));
    }
    u16* brow = &Bext[n * 200 + dseg * 16];
#pragma unroll
    for (int q = 0; q < 4; ++q) {
      *(ushort4*)&brow[q * 4] = hv[q];
      *(ushort4*)&brow[64 + q * 4] = hv[q];
      *(ushort4*)&brow[128 + q * 4] = lv[q];
    }
  }
  __syncthreads();

  const int lane = tid & 63;
  const int w = tid >> 6;
  const int fr = lane & 15, s_ = lane >> 4;
  f32x4 facc[4];
#pragma unroll
  for (int n = 0; n < 4; ++n)
#pragma unroll
    for (int r = 0; r < 4; ++r) facc[n][r] = 0.f;
  const u16* arow = &Aext[(w * 16 + fr) * 200 + s_ * 8];
#pragma unroll
  for (int kk = 0; kk < 6; ++kk) {
    bf16x8 av = *(const bf16x8*)&arow[kk * 32];
#pragma unroll
    for (int n = 0; n < 4; ++n) {
      bf16x8 bv = *(const bf16x8*)&Bext[(n * 16 + fr) * 200 + kk * 32 + s_ * 8];
      facc[n] = __builtin_amdgcn_mfma_f32_16x16x32_bf16(av, bv, facc[n], 0, 0, 0);
    }
  }

  const float s0 = qnodes[0], s1 = qnodes[1];
  const float sq0 = sqrtf(2.f * fmaxf(s0, 0.f));
  const float sq1 = sqrtf(2.f * fmaxf(s1, 0.f));
  const float sc0 = sqrtf(fmaxf(qweights[0], 0.f)) * 0.17677669529663687f;
  const float sc1 = sqrtf(fmaxf(qweights[1], 0.f)) * 0.17677669529663687f;
  float* __restrict__ dst = which ? kf : qf;
  const size_t base = ((size_t)bh * T_ + t0) * FD_;
  const int fg = lane >> 4;
#pragma unroll
  for (int n = 0; n < 4; ++n) {
    const int feat = n * 16 + fr;
    const int ridx = n >> 1;
    const float sq = ridx ? sq1 : sq0;
    const float so = ridx ? s1 : s0;
    const float sc = ridx ? sc1 : sc0;
#pragma unroll
    for (int j = 0; j < 4; ++j) {
      const int token = w * 16 + fg * 4 + j;
      const float pr = facc[n][j] * rinv_s[token];
      float arg = fminf(fmaxf(pr * sq - so, -20.f), 20.f);
      dst[base + (size_t)token * FD_ + feat] = expf(arg) * sc;
    }
  }
}

// ---------------------------------------------------------------------------
// Per-chunk KV = kf^T @ v and Ksum (unchanged)
// ---------------------------------------------------------------------------
__global__ __launch_bounds__(256) void chunk_sums_k(
    const float* __restrict__ kf, const float* __restrict__ qkv,
    float* __restrict__ kvsum, float* __restrict__ ksum)
{
  const int blk = blockIdx.x;
  const int c = blk % NCH;
  const int bh = blk / NCH;
  const int b = bh / HEADS_, h = bh % HEADS_;
  const int tid = threadIdx.x;
  const int d = tid & 63;
  const int fq = tid >> 6;
  __shared__ float kf_s[16][64];
  __shared__ float v_s[16][64];
  float acc[16];
#pragma unroll
  for (int i = 0; i < 16; ++i) acc[i] = 0.f;
  float ks = 0.f;
  for (int t0 = 0; t0 < LCH; t0 += 16) {
#pragma unroll
    for (int l = 0; l < 4; ++l) {
      int idx = tid + l * 256;
      int rr = idx >> 6, cc = idx & 63;
      int t = c * LCH + t0 + rr;
      kf_s[rr][cc] = kf[((size_t)bh * T_ + t) * FD_ + cc];
      v_s[rr][cc] =
          qkv[((size_t)(b * T_ + t)) * 3072 + 2 * EMBED_ + h * HD_ + cc];
    }
    __syncthreads();
#pragma unroll
    for (int tt = 0; tt < 16; ++tt) {
      float vv = v_s[tt][d];
      if (fq == 0) ks += kf_s[tt][d];
#pragma unroll
      for (int i = 0; i < 16; ++i) acc[i] += kf_s[tt][fq * 16 + i] * vv;
    }
    __syncthreads();
  }
#pragma unroll
  for (int i = 0; i < 16; ++i)
    kvsum[(size_t)blk * 4096 + (size_t)(fq * 16 + i) * 64 + d] = acc[i];
  if (fq == 0) ksum[(size_t)blk * 64 + d] = ks;
}

// ---------------------------------------------------------------------------
// Exclusive prefix over chunks — register-resident, 512 blocks
// ---------------------------------------------------------------------------
__global__ __launch_bounds__(256) void prefix2_k(float* __restrict__ kvsum,
                                                 float* __restrict__ ksum)
{
  const int bh = blockIdx.x >> 4;
  const int eb = blockIdx.x & 15;
  const int e = eb * 256 + threadIdx.x;
  float v[NCH];
  const size_t base = (size_t)bh * NCH * 4096 + e;
#pragma unroll
  for (int c = 0; c < NCH; ++c) v[c] = kvsum[base + (size_t)c * 4096];
  float run = 0.f;
#pragma unroll
  for (int c = 0; c < NCH; ++c) {
    kvsum[base + (size_t)c * 4096] = run;
    run += v[c];
  }
  if (eb == 0 && threadIdx.x < 64) {
    const size_t kb = (size_t)bh * NCH * 64 + threadIdx.x;
    float w[NCH];
#pragma unroll
    for (int c = 0; c < NCH; ++c) w[c] = ksum[kb + c * 64];
    float r2 = 0.f;
#pragma unroll
    for (int c = 0; c < NCH; ++c) {
      ksum[kb + c * 64] = r2;
      r2 += w[c];
    }
  }
}

// ---------------------------------------------------------------------------
// Per-chunk causal attention; fused fp16 output [4096][1024] (or f32 fallback)
// ---------------------------------------------------------------------------
__global__ __launch_bounds__(256) void chunk_attn3_k(
    const float* __restrict__ qf, const float* __restrict__ kf,
    const float* __restrict__ qkv_v, const float* __restrict__ kvsum,
    const float* __restrict__ ksum, u16* __restrict__ out_f16,
    float* __restrict__ out_f32, int lda)
{
  const int blk = blockIdx.x;
  const int c = blk & (NCH - 1);
  const int bh = blk / NCH;
  const int b = bh / HEADS_, h = bh % HEADS_;
  const int tid = threadIdx.x;
  __shared__ float kf_s[64][64];
  __shared__ float v_s[64][64];
  __shared__ float S_s[64][64];
  __shared__ float qf_s[64][64];
  {
    const int r = tid >> 2, q4 = (tid & 3) * 16;
    const size_t fbase = ((size_t)bh * T_ + c * LCH + r) * FD_ + q4;
    const size_t vbase =
        ((size_t)(b * T_ + c * LCH + r)) * 3072 + 2 * EMBED_ + h * HD_ + q4;
    const size_t sbase = (size_t)blk * 4096 + (size_t)r * 64 + q4;
#pragma unroll
    for (int j = 0; j < 16; j += 4) {
      *(float4*)&kf_s[r][q4 + j] = *(const float4*)&kf[fbase + j];
      *(float4*)&qf_s[r][q4 + j] = *(const float4*)&qf[fbase + j];
      *(float4*)&S_s[r][q4 + j] = *(const float4*)&kvsum[sbase + j];
      *(float4*)&v_s[r][q4 + j] = *(const float4*)&qkv_v[vbase + j];
    }
  }
  __syncthreads();
  const int l = tid & 63;
  const int t = (tid >> 6) * 16 + (l & 15);
  const int dq = l >> 4, d0 = dq * 16;

  float q_r[64];
#pragma unroll
  for (int j = 0; j < 64; j += 4)
    *(float4*)&q_r[j] = *(const float4*)&qf_s[t][j];

  float ctx[16];
#pragma unroll
  for (int j = 0; j < 16; ++j) ctx[j] = 0.f;
  float den = 0.f, den2 = 0.f;

#pragma unroll 4
  for (int f = 0; f < 64; ++f) {
    const float qv = q_r[f];
#pragma unroll
    for (int j = 0; j < 16; j += 4) {
      float4 s4 = *(const float4*)&S_s[f][d0 + j];
      ctx[j + 0] += qv * s4.x;
      ctx[j + 1] += qv * s4.y;
      ctx[j + 2] += qv * s4.z;
      ctx[j + 3] += qv * s4.w;
    }
  }
  {
    const float* svp = &ksum[(size_t)blk * 64 + d0];
#pragma unroll
    for (int j = 0; j < 16; ++j) den += q_r[d0 + j] * svp[j];
  }

  for (int s = 0; s < LCH; ++s) {
    float a = 0.f;
#pragma unroll
    for (int j = 0; j < 16; j += 4) {
      float4 k4 = *(const float4*)&kf_s[s][d0 + j];
      a += q_r[d0 + j] * k4.x + q_r[d0 + j + 1] * k4.y +
           q_r[d0 + j + 2] * k4.z + q_r[d0 + j + 3] * k4.w;
    }
    a += __shfl_xor(a, 16, 64);
    a += __shfl_xor(a, 32, 64);
    if (s <= t) {
      den2 += a;
#pragma unroll
      for (int j = 0; j < 16; j += 4) {
        float4 v4 = *(const float4*)&v_s[s][d0 + j];
        ctx[j + 0] += a * v4.x;
        ctx[j + 1] += a * v4.y;
        ctx[j + 2] += a * v4.z;
        ctx[j + 3] += a * v4.w;
      }
    }
  }
  den += __shfl_xor(den, 16, 64);
  den += __shfl_xor(den, 32, 64);
  const float rden = 1.f / fmaxf(den + den2, 1e-6f);

  if (out_f16) {
    union { _Float16 hx[16]; uint4 q[2]; } pk;
#pragma unroll
    for (int j = 0; j < 16; ++j) pk.hx[j] = (_Float16)(ctx[j] * rden);
    const size_t be = ((size_t)(b * T_ + c * LCH + t)) * 1024 + h * HD_ + d0;
    *(uint4*)&out_f16[be] = pk.q[0];
    *(uint4*)&out_f16[be + 8] = pk.q[1];
  } else {
    float* op =
        &out_f32[((size_t)(b * T_ + c * LCH + t)) * lda + h * HD_ + d0];
#pragma unroll
    for (int j = 0; j < 16; j += 4) {
      float4 o;
      o.x = ctx[j + 0] * rden;
      o.y = ctx[j + 1] * rden;
      o.z = ctx[j + 2] * rden;
      o.w = ctx[j + 3] * rden;
      *(float4*)&op[j] = o;
    }
  }
}

// ---------------------------------------------------------------------------
extern "C" void kernel_launch(void* const* d_in, const int* in_sizes, int n_in,
                              void* d_out, int out_size, void* d_ws,
                              size_t ws_size, hipStream_t stream)
{
  (void)in_sizes; (void)n_in; (void)out_size;
  const float* x = (const float*)d_in[0];
  const float* Wqkv = (const float*)d_in[1];
  const float* bqkv = (const float*)d_in[2];
  const float* Wout = (const float*)d_in[3];
  const float* bout = (const float*)d_in[4];
  const float* omega = (const float*)d_in[5];
  const float* qnodes = (const float*)d_in[6];
  const float* qweights = (const float*)d_in[7];
  float* out = (float*)d_out;

  float* ws = (float*)d_ws;
  const size_t QKV_F = (size_t)B_ * T_ * 3 * EMBED_;   // 12,582,912
  const size_t F_F = (size_t)BH_ * T_ * FD_;           // 4,194,304
  const size_t KV_F = (size_t)BH_ * NCH * FD_ * HD_;   // 4,194,304
  const size_t KS_F = (size_t)BH_ * NCH * FD_;         // 65,536
  const size_t XH_E = (size_t)B_ * T_ * EMBED_;        // 4,194,304 u16
  const size_t WQ_E = (size_t)3 * EMBED_ * EMBED_;     // 3,145,728 u16
  const size_t WO_E = (size_t)EMBED_ * EMBED_;         // 1,048,576 u16

  float* qkv = ws;
  float* qf = qkv + QKV_F;
  float* kf = qf + F_F;
  float* kvsum = kf + F_F;
  float* ksum = kvsum + KV_F;
  u16* x_f16 = (u16*)(ksum + KS_F);
  u16* wq_f16t = x_f16 + XH_E;
  u16* wo_f16t = wq_f16t + WQ_E;
  const size_t needed =
      (QKV_F + 2 * F_F + KV_F + KS_F) * 4 + (XH_E + WQ_E + WO_E) * 2;

  const int MT = B_ * T_;

  if (ws_size >= needed) {
    u16* attn_f16 = x_f16;  // x_f16 dead after gemm1

    cvt_x_f16_k<<<dim3(2048), 256, 0, stream>>>(x, x_f16, MT * EMBED_ / 8);
    cvt_w_f16t_k<<<dim3(96, 32), 256, 0, stream>>>(Wqkv, wq_f16t, 3 * EMBED_);
    gemm_f16_k<<<dim3(24, 32), 256, 0, stream>>>(x_f16, wq_f16t, bqkv, qkv,
                                                 1024, 3 * EMBED_);
    features_mfma_k<<<dim3(T_ / 64, HEADS_, 4), 256, 0, stream>>>(
        qkv, omega, qnodes, qweights, qf, kf);
    chunk_sums_k<<<dim3(BH_ * NCH), 256, 0, stream>>>(kf, qkv, kvsum, ksum);
    prefix2_k<<<dim3(512), 256, 0, stream>>>(kvsum, ksum);
    cvt_w_f16t_k<<<dim3(32, 32), 256, 0, stream>>>(Wout, wo_f16t, EMBED_);
    chunk_attn3_k<<<dim3(BH_ * NCH), 256, 0, stream>>>(
        qf, kf, qkv, kvsum, ksum, attn_f16, nullptr, 0);
    gemm_f16_n64_k<<<dim3(16, 32), 256, 0, stream>>>(attn_f16, wo_f16t, bout,
                                                     out, 1024, EMBED_);
  } else {
    gemm_bias_k<<<dim3(24, 32), 256, 0, stream>>>(
        x, Wqkv, bqkv, qkv, MT, 3 * EMBED_, EMBED_, EMBED_, 3 * EMBED_,
        3 * EMBED_);
    features_mfma_k<<<dim3(T_ / 64, HEADS_, 4), 256, 0, stream>>>(
        qkv, omega, qnodes, qweights, qf, kf);
    chunk_sums_k<<<dim3(BH_ * NCH), 256, 0, stream>>>(kf, qkv, kvsum, ksum);
    prefix2_k<<<dim3(512), 256, 0, stream>>>(kvsum, ksum);
    chunk_attn3_k<<<dim3(BH_ * NCH), 256, 0, stream>>>(
        qf, kf, qkv, kvsum, ksum, nullptr, qkv, 3 * EMBED_);
    gemm_bias_k<<<dim3(8, 32), 256, 0, stream>>>(
        qkv, Wout, bout, out, MT, EMBED_, EMBED_, 3 * EMBED_, EMBED_, EMBED_);
  }
}

// Round 11
// 221.043 us; speedup vs baseline: 3.6827x; 1.2295x over previous
//
#include <hip/hip_runtime.h>
#include <cstddef>
#include <cstdint>

#define B_ 2
#define T_ 2048
#define EMBED_ 1024
#define HEADS_ 16
#define HD_ 64
#define M_ 32
#define R_ 2
#define FD_ 64
#define LCH 64
#define NCH (T_ / LCH)  // 32
#define BH_ (B_ * HEADS_)

typedef unsigned short u16;
using bf16x8 = __attribute__((ext_vector_type(8))) short;
using f16x8 = __attribute__((ext_vector_type(8))) _Float16;
using f32x4 = __attribute__((ext_vector_type(4))) float;

__device__ __forceinline__ u16 f2bf(float f) {
  uint32_t u = __float_as_uint(f);
  u += 0x7FFF + ((u >> 16) & 1);
  return (u16)(u >> 16);
}
__device__ __forceinline__ float bf2f(u16 h) {
  return __uint_as_float(((uint32_t)h) << 16);
}
__device__ __forceinline__ u16 f2h(float f) {
  _Float16 h = (_Float16)f;
  return *(u16*)&h;
}
__device__ __forceinline__ _Float16 f2hh(float f) { return (_Float16)f; }

__device__ __forceinline__ void gload_lds16(const void* g, void* l) {
  __builtin_amdgcn_global_load_lds(
      (const __attribute__((address_space(1))) unsigned int*)g,
      (__attribute__((address_space(3))) unsigned int*)l, 16, 0, 0);
}

// paired-row swizzle (round-5 proven: SQ_LDS_BANK_CONFLICT == 0)
__device__ __forceinline__ int swz_off(int R, int s) {
  return (R >> 1) * 64 + (((((R & 1) << 2) | s) ^ ((R >> 1) & 7)) * 8);
}

// ---------------------------------------------------------------------------
// fp16 MFMA GEMM, 128x128 tile, swizzled LDS, dbuf (round-10 proven)
// ---------------------------------------------------------------------------
__global__ __launch_bounds__(256) void gemm_f16_k(
    const u16* __restrict__ A, const u16* __restrict__ Bt,
    const float* __restrict__ bias, float* __restrict__ C, int K, int ldc)
{
  __shared__ u16 As[2][128 * 32];
  __shared__ u16 Bs[2][128 * 32];
  const int tid = threadIdx.x;
  const int row0 = blockIdx.y * 128, col0 = blockIdx.x * 128;
  const int lane = tid & 63;
  const int w = tid >> 6;
  const int wr = tid >> 7, wc = (tid >> 6) & 1;
  f32x4 acc[4][4];
#pragma unroll
  for (int m = 0; m < 4; ++m)
#pragma unroll
    for (int n = 0; n < 4; ++n)
#pragma unroll
      for (int r = 0; r < 4; ++r) acc[m][n][r] = 0.f;

  const int u_ = (lane & 7) ^ (lane >> 3);
  const int srow = w * 16 + 2 * (lane >> 3) + (u_ >> 2);
  const int skp = (u_ & 3) * 8;
  const u16* Agp = A + (size_t)(row0 + srow) * K + skp;
  const u16* Bgp = Bt + (size_t)(col0 + srow) * K + skp;
  const int wb = w * 512;

  const int fr = lane & 15;
  const int s_ = lane >> 4;
  int aoff[4], boff[4];
#pragma unroll
  for (int m = 0; m < 4; ++m) aoff[m] = swz_off(wr * 64 + m * 16 + fr, s_);
#pragma unroll
  for (int n = 0; n < 4; ++n) boff[n] = swz_off(wc * 64 + n * 16 + fr, s_);

  const int nt = K >> 5;
  gload_lds16(Agp, &As[0][wb]);
  gload_lds16(Agp + (size_t)64 * K, &As[0][wb + 2048]);
  gload_lds16(Bgp, &Bs[0][wb]);
  gload_lds16(Bgp + (size_t)64 * K, &Bs[0][wb + 2048]);
  __syncthreads();

  for (int t = 0; t < nt; ++t) {
    const int cur = t & 1;
    if (t + 1 < nt) {
      const int k0 = (t + 1) * 32;
      gload_lds16(Agp + k0, &As[cur ^ 1][wb]);
      gload_lds16(Agp + k0 + (size_t)64 * K, &As[cur ^ 1][wb + 2048]);
      gload_lds16(Bgp + k0, &Bs[cur ^ 1][wb]);
      gload_lds16(Bgp + k0 + (size_t)64 * K, &Bs[cur ^ 1][wb + 2048]);
    }
    f16x8 a[4], b[4];
#pragma unroll
    for (int m = 0; m < 4; ++m) a[m] = *(const f16x8*)&As[cur][aoff[m]];
#pragma unroll
    for (int n = 0; n < 4; ++n) b[n] = *(const f16x8*)&Bs[cur][boff[n]];
#pragma unroll
    for (int m = 0; m < 4; ++m)
#pragma unroll
      for (int n = 0; n < 4; ++n)
        acc[m][n] = __builtin_amdgcn_mfma_f32_16x16x32_f16(a[m], b[n],
                                                           acc[m][n], 0, 0, 0);
    __syncthreads();
  }
  const int fg = lane >> 4;
#pragma unroll
  for (int m = 0; m < 4; ++m) {
#pragma unroll
    for (int n = 0; n < 4; ++n) {
      const int col = col0 + wc * 64 + n * 16 + fr;
      const float bv = bias[col];
#pragma unroll
      for (int r = 0; r < 4; ++r) {
        const int row = row0 + wr * 64 + m * 16 + fg * 4 + r;
        C[(size_t)row * ldc + col] = acc[m][n][r] + bv;
      }
    }
  }
}

// ---------------------------------------------------------------------------
// fp16 MFMA GEMM, 128x64 tile, dbuf (round-10 proven)
// ---------------------------------------------------------------------------
__global__ __launch_bounds__(256) void gemm_f16_n64_k(
    const u16* __restrict__ A, const u16* __restrict__ Bt,
    const float* __restrict__ bias, float* __restrict__ C, int K, int ldc)
{
  __shared__ u16 As[2][128 * 32];
  __shared__ u16 Bs[2][64 * 32];
  const int tid = threadIdx.x;
  const int row0 = blockIdx.y * 128, col0 = blockIdx.x * 64;
  const int lane = tid & 63;
  const int w = tid >> 6;
  f32x4 acc[2][4];
#pragma unroll
  for (int m = 0; m < 2; ++m)
#pragma unroll
    for (int n = 0; n < 4; ++n)
#pragma unroll
      for (int r = 0; r < 4; ++r) acc[m][n][r] = 0.f;

  const int u_ = (lane & 7) ^ (lane >> 3);
  const int srow = w * 16 + 2 * (lane >> 3) + (u_ >> 2);
  const int skp = (u_ & 3) * 8;
  const u16* Agp = A + (size_t)(row0 + srow) * K + skp;
  const u16* Bgp = Bt + (size_t)(col0 + srow) * K + skp;
  const int wb = w * 512;

  const int fr = lane & 15;
  const int s_ = lane >> 4;
  int aoff[2], boff[4];
#pragma unroll
  for (int m = 0; m < 2; ++m) aoff[m] = swz_off(w * 32 + m * 16 + fr, s_);
#pragma unroll
  for (int n = 0; n < 4; ++n) boff[n] = swz_off(n * 16 + fr, s_);

  const int nt = K >> 5;
  gload_lds16(Agp, &As[0][wb]);
  gload_lds16(Agp + (size_t)64 * K, &As[0][wb + 2048]);
  gload_lds16(Bgp, &Bs[0][wb]);
  __syncthreads();

  for (int t = 0; t < nt; ++t) {
    const int cur = t & 1;
    if (t + 1 < nt) {
      const int k0 = (t + 1) * 32;
      gload_lds16(Agp + k0, &As[cur ^ 1][wb]);
      gload_lds16(Agp + k0 + (size_t)64 * K, &As[cur ^ 1][wb + 2048]);
      gload_lds16(Bgp + k0, &Bs[cur ^ 1][wb]);
    }
    f16x8 a[2], b[4];
#pragma unroll
    for (int m = 0; m < 2; ++m) a[m] = *(const f16x8*)&As[cur][aoff[m]];
#pragma unroll
    for (int n = 0; n < 4; ++n) b[n] = *(const f16x8*)&Bs[cur][boff[n]];
#pragma unroll
    for (int m = 0; m < 2; ++m)
#pragma unroll
      for (int n = 0; n < 4; ++n)
        acc[m][n] = __builtin_amdgcn_mfma_f32_16x16x32_f16(a[m], b[n],
                                                           acc[m][n], 0, 0, 0);
    __syncthreads();
  }
  const int fg = lane >> 4;
#pragma unroll
  for (int m = 0; m < 2; ++m) {
#pragma unroll
    for (int n = 0; n < 4; ++n) {
      const int col = col0 + n * 16 + fr;
      const float bv = bias[col];
#pragma unroll
      for (int r = 0; r < 4; ++r) {
        const int row = row0 + w * 32 + m * 16 + fg * 4 + r;
        C[(size_t)row * ldc + col] = acc[m][n][r] + bv;
      }
    }
  }
}

// ---------------------------------------------------------------------------
// fp32 -> fp16 elementwise convert (8 elems/thread)
// ---------------------------------------------------------------------------
__global__ __launch_bounds__(256) void cvt_x_f16_k(const float* __restrict__ X,
                                                   u16* __restrict__ Y, int n8)
{
  const int idx = blockIdx.x * 256 + threadIdx.x;
  if (idx >= n8) return;
  float4 a = *(const float4*)&X[(size_t)idx * 8];
  float4 b = *(const float4*)&X[(size_t)idx * 8 + 4];
  ushort4 o0, o1;
  o0.x = f2h(a.x); o0.y = f2h(a.y); o0.z = f2h(a.z); o0.w = f2h(a.w);
  o1.x = f2h(b.x); o1.y = f2h(b.y); o1.z = f2h(b.z); o1.w = f2h(b.w);
  *(ushort4*)&Y[(size_t)idx * 8] = o0;
  *(ushort4*)&Y[(size_t)idx * 8 + 4] = o1;
}

// ---------------------------------------------------------------------------
// transpose + convert W [1024][N] fp32 -> Wt [N][1024] fp16
// ---------------------------------------------------------------------------
__global__ __launch_bounds__(256) void cvt_w_f16t_k(const float* __restrict__ W,
                                                    u16* __restrict__ Wt, int N)
{
  __shared__ float tile[32][33];
  const int n0 = blockIdx.x * 32, k0 = blockIdx.y * 32;
  const int tx = threadIdx.x & 31, ty = threadIdx.x >> 5;
#pragma unroll
  for (int i = 0; i < 4; ++i)
    tile[ty + i * 8][tx] = W[(size_t)(k0 + ty + i * 8) * N + n0 + tx];
  __syncthreads();
#pragma unroll
  for (int i = 0; i < 4; ++i) {
    const int n = ty + i * 8;
    Wt[(size_t)(n0 + n) * 1024 + k0 + tx] = f2h(tile[tx][n]);
  }
}

// ---------------------------------------------------------------------------
// fallback fp32 GEMM (round-1, proven)
// ---------------------------------------------------------------------------
__global__ __launch_bounds__(256) void gemm_bias_k(
    const float* __restrict__ A, const float* __restrict__ Bm,
    const float* __restrict__ bias, float* __restrict__ C,
    int Mdim, int Ndim, int Kdim, int lda, int ldb, int ldc)
{
  __shared__ float Asm[16][128];
  __shared__ float Bsm[16][128];
  const int tid = threadIdx.x;
  const int row0 = blockIdx.y * 128;
  const int col0 = blockIdx.x * 128;
  const int ty = tid >> 4, tx = tid & 15;
  float acc[8][8];
#pragma unroll
  for (int i = 0; i < 8; ++i)
#pragma unroll
    for (int j = 0; j < 8; ++j) acc[i][j] = 0.f;

  for (int k0 = 0; k0 < Kdim; k0 += 16) {
#pragma unroll
    for (int l = 0; l < 2; ++l) {
      int f = tid * 2 + l;
      int ar = f >> 2, aq = f & 3;
      float4 av = *reinterpret_cast<const float4*>(
          &A[(size_t)(row0 + ar) * lda + k0 + aq * 4]);
      Asm[aq * 4 + 0][ar] = av.x;
      Asm[aq * 4 + 1][ar] = av.y;
      Asm[aq * 4 + 2][ar] = av.z;
      Asm[aq * 4 + 3][ar] = av.w;
      int br = f >> 5, bc = f & 31;
      *reinterpret_cast<float4*>(&Bsm[br][bc * 4]) =
          *reinterpret_cast<const float4*>(
              &Bm[(size_t)(k0 + br) * ldb + col0 + bc * 4]);
    }
    __syncthreads();
#pragma unroll
    for (int kk = 0; kk < 16; ++kk) {
      float a[8], b[8];
      *reinterpret_cast<float4*>(&a[0]) =
          *reinterpret_cast<const float4*>(&Asm[kk][ty * 8]);
      *reinterpret_cast<float4*>(&a[4]) =
          *reinterpret_cast<const float4*>(&Asm[kk][ty * 8 + 4]);
      *reinterpret_cast<float4*>(&b[0]) =
          *reinterpret_cast<const float4*>(&Bsm[kk][tx * 8]);
      *reinterpret_cast<float4*>(&b[4]) =
          *reinterpret_cast<const float4*>(&Bsm[kk][tx * 8 + 4]);
#pragma unroll
      for (int i = 0; i < 8; ++i)
#pragma unroll
        for (int j = 0; j < 8; ++j) acc[i][j] += a[i] * b[j];
    }
    __syncthreads();
  }
#pragma unroll
  for (int i = 0; i < 8; ++i) {
    int r = row0 + ty * 8 + i;
#pragma unroll
    for (int j = 0; j < 8; j += 4) {
      int c = col0 + tx * 8 + j;
      float4 o;
      o.x = acc[i][j + 0] + bias[c + 0];
      o.y = acc[i][j + 1] + bias[c + 1];
      o.z = acc[i][j + 2] + bias[c + 2];
      o.w = acc[i][j + 3] + bias[c + 3];
      *reinterpret_cast<float4*>(&C[(size_t)r * ldc + c]) = o;
    }
  }
}

// ---------------------------------------------------------------------------
// Laplace features via MFMA (bf16 hi/lo, K_ext=192) — round-5 proven
// ---------------------------------------------------------------------------
__global__ __launch_bounds__(256) void features_mfma_k(
    const float* __restrict__ qkv, const float* __restrict__ omega,
    const float* __restrict__ qnodes, const float* __restrict__ qweights,
    float* __restrict__ qf, float* __restrict__ kf)
{
  __shared__ u16 Aext[64 * 200];
  __shared__ u16 Bext[64 * 200];
  __shared__ float rinv_s[64];
  const int tid = threadIdx.x;
  const int t0 = blockIdx.x * 64;
  const int h = blockIdx.y;
  const int b = blockIdx.z & 1;
  const int which = blockIdx.z >> 1;
  const int bh = b * HEADS_ + h;

  {
    const int row = tid >> 2;
    const int seg = (tid & 3) * 16;
    const float* xsrc = &qkv[((size_t)(b * T_ + t0 + row)) * 3072 +
                             which * 1024 + h * 64 + seg];
    float xv[16];
#pragma unroll
    for (int q = 0; q < 4; ++q)
      *(float4*)&xv[q * 4] = *(const float4*)&xsrc[q * 4];
    float ss = 0.f;
#pragma unroll
    for (int j = 0; j < 16; ++j) ss += xv[j] * xv[j];
    ss += __shfl_xor(ss, 1, 64);
    ss += __shfl_xor(ss, 2, 64);
    if ((tid & 3) == 0) rinv_s[row] = 1.f / fmaxf(sqrtf(ss), 1e-12f);
    ushort4 hv[4], lv[4];
    u16* hp = (u16*)hv; u16* lp = (u16*)lv;
#pragma unroll
    for (int j = 0; j < 16; ++j) {
      u16 hh = f2bf(xv[j]);
      hp[j] = hh;
      lp[j] = f2bf(xv[j] - bf2f(hh));
    }
    u16* arow = &Aext[row * 200 + seg];
#pragma unroll
    for (int q = 0; q < 4; ++q) {
      *(ushort4*)&arow[q * 4] = hv[q];
      *(ushort4*)&arow[64 + q * 4] = lv[q];
      *(ushort4*)&arow[128 + q * 4] = hv[q];
    }
  }
  {
    const int r_o = tid >> 7;
    const int dseg = (tid >> 5) & 3;
    const int m_o = tid & 31;
    const int n = r_o * 32 + m_o;
    const size_t obase =
        (((size_t)(r_o * HEADS_ + h)) * HD_ + dseg * 16) * M_ + m_o;
    ushort4 hv[4], lv[4];
    u16* hp = (u16*)hv; u16* lp = (u16*)lv;
#pragma unroll
    for (int i = 0; i < 16; ++i) {
      float v = omega[obase + (size_t)i * M_];
      u16 hh = f2bf(v);
      hp[i] = hh;
      lp[i] = f2bf(v - bf2f(hh));
    }
    u16* brow = &Bext[n * 200 + dseg * 16];
#pragma unroll
    for (int q = 0; q < 4; ++q) {
      *(ushort4*)&brow[q * 4] = hv[q];
      *(ushort4*)&brow[64 + q * 4] = hv[q];
      *(ushort4*)&brow[128 + q * 4] = lv[q];
    }
  }
  __syncthreads();

  const int lane = tid & 63;
  const int w = tid >> 6;
  const int fr = lane & 15, s_ = lane >> 4;
  f32x4 facc[4];
#pragma unroll
  for (int n = 0; n < 4; ++n)
#pragma unroll
    for (int r = 0; r < 4; ++r) facc[n][r] = 0.f;
  const u16* arow = &Aext[(w * 16 + fr) * 200 + s_ * 8];
#pragma unroll
  for (int kk = 0; kk < 6; ++kk) {
    bf16x8 av = *(const bf16x8*)&arow[kk * 32];
#pragma unroll
    for (int n = 0; n < 4; ++n) {
      bf16x8 bv = *(const bf16x8*)&Bext[(n * 16 + fr) * 200 + kk * 32 + s_ * 8];
      facc[n] = __builtin_amdgcn_mfma_f32_16x16x32_bf16(av, bv, facc[n], 0, 0, 0);
    }
  }

  const float s0 = qnodes[0], s1 = qnodes[1];
  const float sq0 = sqrtf(2.f * fmaxf(s0, 0.f));
  const float sq1 = sqrtf(2.f * fmaxf(s1, 0.f));
  const float sc0 = sqrtf(fmaxf(qweights[0], 0.f)) * 0.17677669529663687f;
  const float sc1 = sqrtf(fmaxf(qweights[1], 0.f)) * 0.17677669529663687f;
  float* __restrict__ dst = which ? kf : qf;
  const size_t base = ((size_t)bh * T_ + t0) * FD_;
  const int fg = lane >> 4;
#pragma unroll
  for (int n = 0; n < 4; ++n) {
    const int feat = n * 16 + fr;
    const int ridx = n >> 1;
    const float sq = ridx ? sq1 : sq0;
    const float so = ridx ? s1 : s0;
    const float sc = ridx ? sc1 : sc0;
#pragma unroll
    for (int j = 0; j < 4; ++j) {
      const int token = w * 16 + fg * 4 + j;
      const float pr = facc[n][j] * rinv_s[token];
      float arg = fminf(fmaxf(pr * sq - so, -20.f), 20.f);
      dst[base + (size_t)token * FD_ + feat] = expf(arg) * sc;
    }
  }
}

// ---------------------------------------------------------------------------
// Per-chunk KV = kf^T @ v and Ksum (unchanged)
// ---------------------------------------------------------------------------
__global__ __launch_bounds__(256) void chunk_sums_k(
    const float* __restrict__ kf, const float* __restrict__ qkv,
    float* __restrict__ kvsum, float* __restrict__ ksum)
{
  const int blk = blockIdx.x;
  const int c = blk % NCH;
  const int bh = blk / NCH;
  const int b = bh / HEADS_, h = bh % HEADS_;
  const int tid = threadIdx.x;
  const int d = tid & 63;
  const int fq = tid >> 6;
  __shared__ float kf_s[16][64];
  __shared__ float v_s[16][64];
  float acc[16];
#pragma unroll
  for (int i = 0; i < 16; ++i) acc[i] = 0.f;
  float ks = 0.f;
  for (int t0 = 0; t0 < LCH; t0 += 16) {
#pragma unroll
    for (int l = 0; l < 4; ++l) {
      int idx = tid + l * 256;
      int rr = idx >> 6, cc = idx & 63;
      int t = c * LCH + t0 + rr;
      kf_s[rr][cc] = kf[((size_t)bh * T_ + t) * FD_ + cc];
      v_s[rr][cc] =
          qkv[((size_t)(b * T_ + t)) * 3072 + 2 * EMBED_ + h * HD_ + cc];
    }
    __syncthreads();
#pragma unroll
    for (int tt = 0; tt < 16; ++tt) {
      float vv = v_s[tt][d];
      if (fq == 0) ks += kf_s[tt][d];
#pragma unroll
      for (int i = 0; i < 16; ++i) acc[i] += kf_s[tt][fq * 16 + i] * vv;
    }
    __syncthreads();
  }
#pragma unroll
  for (int i = 0; i < 16; ++i)
    kvsum[(size_t)blk * 4096 + (size_t)(fq * 16 + i) * 64 + d] = acc[i];
  if (fq == 0) ksum[(size_t)blk * 64 + d] = ks;
}

// ---------------------------------------------------------------------------
// Exclusive prefix over chunks — register-resident, 512 blocks
// ---------------------------------------------------------------------------
__global__ __launch_bounds__(256) void prefix2_k(float* __restrict__ kvsum,
                                                 float* __restrict__ ksum)
{
  const int bh = blockIdx.x >> 4;
  const int eb = blockIdx.x & 15;
  const int e = eb * 256 + threadIdx.x;
  float v[NCH];
  const size_t base = (size_t)bh * NCH * 4096 + e;
#pragma unroll
  for (int c = 0; c < NCH; ++c) v[c] = kvsum[base + (size_t)c * 4096];
  float run = 0.f;
#pragma unroll
  for (int c = 0; c < NCH; ++c) {
    kvsum[base + (size_t)c * 4096] = run;
    run += v[c];
  }
  if (eb == 0 && threadIdx.x < 64) {
    const size_t kb = (size_t)bh * NCH * 64 + threadIdx.x;
    float w[NCH];
#pragma unroll
    for (int c = 0; c < NCH; ++c) w[c] = ksum[kb + c * 64];
    float r2 = 0.f;
#pragma unroll
    for (int c = 0; c < NCH; ++c) {
      ksum[kb + c * 64] = r2;
      r2 += w[c];
    }
  }
}

// ---------------------------------------------------------------------------
// MFMA per-chunk causal attention.
// CTX = QF@S_prev + tril(QF@KF^T)@V ; den = QF.ksum + rowsum(tril(..)).
// P and S scaled by 2^-10 (cancels in ctx/den) to stay in fp16 range.
// LDS tiles fp16 stride 72 (16B-aligned rows). 4 waves; wave w owns rows
// [w*16, w*16+16) of the 64x64 output; 24 MFMA/wave.
// ---------------------------------------------------------------------------
__global__ __launch_bounds__(256) void chunk_attn4_k(
    const float* __restrict__ qf, const float* __restrict__ kf,
    const float* __restrict__ qkv_v, const float* __restrict__ kvsum,
    const float* __restrict__ ksum, u16* __restrict__ out_f16)
{
  constexpr float SCL = 1.f / 1024.f;      // 2^-10
  constexpr float DEN_EPS = 1e-6f / 1024.f;
  __shared__ u16 qf_h[64 * 72];
  __shared__ u16 kf_h[64 * 72];
  __shared__ u16 st_h[64 * 72];  // S^T  [d][f], scaled
  __shared__ u16 vt_h[64 * 72];  // V^T  [d][s]
  __shared__ u16 p_h[64 * 72];   // P    [t][s], scaled
  __shared__ float den_s[64];    // scaled denominator per row
  const int blk = blockIdx.x;
  const int c = blk & (NCH - 1);
  const int bh = blk / NCH;
  const int b = bh / HEADS_, h = bh % HEADS_;
  const int tid = threadIdx.x;

  // ---- staging: fp32 -> fp16 LDS (+S,V transposes), den_hist
  {
    const int r = tid >> 2, q4 = (tid & 3) * 16;
    const size_t fbase = ((size_t)bh * T_ + c * LCH + r) * FD_ + q4;
    const size_t vbase =
        ((size_t)(b * T_ + c * LCH + r)) * 3072 + 2 * EMBED_ + h * HD_ + q4;
    const size_t sbase = (size_t)blk * 4096 + (size_t)r * 64 + q4;
    float qv[16], kv[16], sv[16], vv[16], ks[16];
#pragma unroll
    for (int j = 0; j < 16; j += 4) {
      *(float4*)&qv[j] = *(const float4*)&qf[fbase + j];
      *(float4*)&kv[j] = *(const float4*)&kf[fbase + j];
      *(float4*)&sv[j] = *(const float4*)&kvsum[sbase + j];
      *(float4*)&vv[j] = *(const float4*)&qkv_v[vbase + j];
      *(float4*)&ks[j] = *(const float4*)&ksum[(size_t)blk * 64 + q4 + j];
    }
    float dh = 0.f;
#pragma unroll
    for (int j = 0; j < 16; ++j) dh += qv[j] * ks[j];
    dh += __shfl_xor(dh, 1, 64);
    dh += __shfl_xor(dh, 2, 64);
    if ((tid & 3) == 0) den_s[r] = dh * SCL;
    // contiguous rows for QF, KF
    ushort4 qo[4], ko[4];
    u16* qp = (u16*)qo; u16* kp = (u16*)ko;
#pragma unroll
    for (int j = 0; j < 16; ++j) { qp[j] = f2h(qv[j]); kp[j] = f2h(kv[j]); }
#pragma unroll
    for (int q = 0; q < 4; ++q) {
      *(ushort4*)&qf_h[r * 72 + q4 + q * 4] = qo[q];
      *(ushort4*)&kf_h[r * 72 + q4 + q * 4] = ko[q];
    }
    // transposed scatter for S^T (scaled), V^T
#pragma unroll
    for (int j = 0; j < 16; ++j) {
      st_h[(q4 + j) * 72 + r] = f2h(sv[j] * SCL);
      vt_h[(q4 + j) * 72 + r] = f2h(vv[j]);
    }
  }
  __syncthreads();

  const int lane = tid & 63;
  const int w = tid >> 6;
  const int fr = lane & 15;
  const int s_ = lane >> 4;
  const int arow = (w * 16 + fr) * 72 + s_ * 8;
  const int trow = w * 16 + s_ * 4;  // + r = this lane's C-rows

  const f16x8 a0 = *(const f16x8*)&qf_h[arow];
  const f16x8 a1 = *(const f16x8*)&qf_h[arow + 32];

  // M2: scores QF@KF^T
  f32x4 sc[4];
#pragma unroll
  for (int n = 0; n < 4; ++n) {
#pragma unroll
    for (int r = 0; r < 4; ++r) sc[n][r] = 0.f;
    const f16x8 b0 = *(const f16x8*)&kf_h[(n * 16 + fr) * 72 + s_ * 8];
    const f16x8 b1 = *(const f16x8*)&kf_h[(n * 16 + fr) * 72 + 32 + s_ * 8];
    sc[n] = __builtin_amdgcn_mfma_f32_16x16x32_f16(a0, b0, sc[n], 0, 0, 0);
    sc[n] = __builtin_amdgcn_mfma_f32_16x16x32_f16(a1, b1, sc[n], 0, 0, 0);
  }
  // M1: ctx_hist QF@S (scaled) into acc
  f32x4 acc[4];
#pragma unroll
  for (int n = 0; n < 4; ++n) {
#pragma unroll
    for (int r = 0; r < 4; ++r) acc[n][r] = 0.f;
    const f16x8 b0 = *(const f16x8*)&st_h[(n * 16 + fr) * 72 + s_ * 8];
    const f16x8 b1 = *(const f16x8*)&st_h[(n * 16 + fr) * 72 + 32 + s_ * 8];
    acc[n] = __builtin_amdgcn_mfma_f32_16x16x32_f16(a0, b0, acc[n], 0, 0, 0);
    acc[n] = __builtin_amdgcn_mfma_f32_16x16x32_f16(a1, b1, acc[n], 0, 0, 0);
  }
  // mask causal, write P (scaled), accumulate den2
  float den2[4] = {0.f, 0.f, 0.f, 0.f};
#pragma unroll
  for (int n = 0; n < 4; ++n) {
    const int scol = n * 16 + fr;
#pragma unroll
    for (int r = 0; r < 4; ++r) {
      const int t = trow + r;
      const float v = (scol <= t) ? sc[n][r] : 0.f;
      p_h[t * 72 + scol] = f2h(v * SCL);
      den2[r] += v;
    }
  }
#pragma unroll
  for (int r = 0; r < 4; ++r) {
    float d = den2[r];
    d += __shfl_xor(d, 1, 64);
    d += __shfl_xor(d, 2, 64);
    d += __shfl_xor(d, 4, 64);
    d += __shfl_xor(d, 8, 64);
    den2[r] = d;
  }
  if (fr == 0) {
#pragma unroll
    for (int r = 0; r < 4; ++r) den_s[trow + r] += den2[r] * SCL;
  }
  __syncthreads();

  // M3: ctx_intra P@V (both scaled consistently) into acc
  const f16x8 p0 = *(const f16x8*)&p_h[arow];
  const f16x8 p1 = *(const f16x8*)&p_h[arow + 32];
#pragma unroll
  for (int n = 0; n < 4; ++n) {
    const f16x8 b0 = *(const f16x8*)&vt_h[(n * 16 + fr) * 72 + s_ * 8];
    const f16x8 b1 = *(const f16x8*)&vt_h[(n * 16 + fr) * 72 + 32 + s_ * 8];
    acc[n] = __builtin_amdgcn_mfma_f32_16x16x32_f16(p0, b0, acc[n], 0, 0, 0);
    acc[n] = __builtin_amdgcn_mfma_f32_16x16x32_f16(p1, b1, acc[n], 0, 0, 0);
  }

  // epilogue: scale cancels in ctx/den
  float rden[4];
#pragma unroll
  for (int r = 0; r < 4; ++r)
    rden[r] = 1.f / fmaxf(den_s[trow + r], DEN_EPS);
#pragma unroll
  for (int n = 0; n < 4; ++n) {
    const int d = n * 16 + fr;
#pragma unroll
    for (int r = 0; r < 4; ++r) {
      const int t = trow + r;
      out_f16[((size_t)(b * T_ + c * LCH + t)) * 1024 + h * HD_ + d] =
          f2h(acc[n][r] * rden[r]);
    }
  }
}

// ---------------------------------------------------------------------------
// fallback per-chunk causal attention (round-10 proven, f32-out path)
// ---------------------------------------------------------------------------
__global__ __launch_bounds__(256) void chunk_attn3_k(
    const float* __restrict__ qf, const float* __restrict__ kf,
    const float* __restrict__ qkv_v, const float* __restrict__ kvsum,
    const float* __restrict__ ksum, float* __restrict__ out_f32, int lda)
{
  const int blk = blockIdx.x;
  const int c = blk & (NCH - 1);
  const int bh = blk / NCH;
  const int b = bh / HEADS_, h = bh % HEADS_;
  const int tid = threadIdx.x;
  __shared__ float kf_s[64][64];
  __shared__ float v_s[64][64];
  __shared__ float S_s[64][64];
  __shared__ float qf_s[64][64];
  {
    const int r = tid >> 2, q4 = (tid & 3) * 16;
    const size_t fbase = ((size_t)bh * T_ + c * LCH + r) * FD_ + q4;
    const size_t vbase =
        ((size_t)(b * T_ + c * LCH + r)) * 3072 + 2 * EMBED_ + h * HD_ + q4;
    const size_t sbase = (size_t)blk * 4096 + (size_t)r * 64 + q4;
#pragma unroll
    for (int j = 0; j < 16; j += 4) {
      *(float4*)&kf_s[r][q4 + j] = *(const float4*)&kf[fbase + j];
      *(float4*)&qf_s[r][q4 + j] = *(const float4*)&qf[fbase + j];
      *(float4*)&S_s[r][q4 + j] = *(const float4*)&kvsum[sbase + j];
      *(float4*)&v_s[r][q4 + j] = *(const float4*)&qkv_v[vbase + j];
    }
  }
  __syncthreads();
  const int l = tid & 63;
  const int t = (tid >> 6) * 16 + (l & 15);
  const int dq = l >> 4, d0 = dq * 16;

  float q_r[64];
#pragma unroll
  for (int j = 0; j < 64; j += 4)
    *(float4*)&q_r[j] = *(const float4*)&qf_s[t][j];

  float ctx[16];
#pragma unroll
  for (int j = 0; j < 16; ++j) ctx[j] = 0.f;
  float den = 0.f, den2 = 0.f;

#pragma unroll 4
  for (int f = 0; f < 64; ++f) {
    const float qv = q_r[f];
#pragma unroll
    for (int j = 0; j < 16; j += 4) {
      float4 s4 = *(const float4*)&S_s[f][d0 + j];
      ctx[j + 0] += qv * s4.x;
      ctx[j + 1] += qv * s4.y;
      ctx[j + 2] += qv * s4.z;
      ctx[j + 3] += qv * s4.w;
    }
  }
  {
    const float* svp = &ksum[(size_t)blk * 64 + d0];
#pragma unroll
    for (int j = 0; j < 16; ++j) den += q_r[d0 + j] * svp[j];
  }

  for (int s = 0; s < LCH; ++s) {
    float a = 0.f;
#pragma unroll
    for (int j = 0; j < 16; j += 4) {
      float4 k4 = *(const float4*)&kf_s[s][d0 + j];
      a += q_r[d0 + j] * k4.x + q_r[d0 + j + 1] * k4.y +
           q_r[d0 + j + 2] * k4.z + q_r[d0 + j + 3] * k4.w;
    }
    a += __shfl_xor(a, 16, 64);
    a += __shfl_xor(a, 32, 64);
    if (s <= t) {
      den2 += a;
#pragma unroll
      for (int j = 0; j < 16; j += 4) {
        float4 v4 = *(const float4*)&v_s[s][d0 + j];
        ctx[j + 0] += a * v4.x;
        ctx[j + 1] += a * v4.y;
        ctx[j + 2] += a * v4.z;
        ctx[j + 3] += a * v4.w;
      }
    }
  }
  den += __shfl_xor(den, 16, 64);
  den += __shfl_xor(den, 32, 64);
  const float rden = 1.f / fmaxf(den + den2, 1e-6f);
  float* op = &out_f32[((size_t)(b * T_ + c * LCH + t)) * lda + h * HD_ + d0];
#pragma unroll
  for (int j = 0; j < 16; j += 4) {
    float4 o;
    o.x = ctx[j + 0] * rden;
    o.y = ctx[j + 1] * rden;
    o.z = ctx[j + 2] * rden;
    o.w = ctx[j + 3] * rden;
    *(float4*)&op[j] = o;
  }
}

// ---------------------------------------------------------------------------
extern "C" void kernel_launch(void* const* d_in, const int* in_sizes, int n_in,
                              void* d_out, int out_size, void* d_ws,
                              size_t ws_size, hipStream_t stream)
{
  (void)in_sizes; (void)n_in; (void)out_size;
  const float* x = (const float*)d_in[0];
  const float* Wqkv = (const float*)d_in[1];
  const float* bqkv = (const float*)d_in[2];
  const float* Wout = (const float*)d_in[3];
  const float* bout = (const float*)d_in[4];
  const float* omega = (const float*)d_in[5];
  const float* qnodes = (const float*)d_in[6];
  const float* qweights = (const float*)d_in[7];
  float* out = (float*)d_out;

  float* ws = (float*)d_ws;
  const size_t QKV_F = (size_t)B_ * T_ * 3 * EMBED_;   // 12,582,912
  const size_t F_F = (size_t)BH_ * T_ * FD_;           // 4,194,304
  const size_t KV_F = (size_t)BH_ * NCH * FD_ * HD_;   // 4,194,304
  const size_t KS_F = (size_t)BH_ * NCH * FD_;         // 65,536
  const size_t XH_E = (size_t)B_ * T_ * EMBED_;        // 4,194,304 u16
  const size_t WQ_E = (size_t)3 * EMBED_ * EMBED_;     // 3,145,728 u16
  const size_t WO_E = (size_t)EMBED_ * EMBED_;         // 1,048,576 u16

  float* qkv = ws;
  float* qf = qkv + QKV_F;
  float* kf = qf + F_F;
  float* kvsum = kf + F_F;
  float* ksum = kvsum + KV_F;
  u16* x_f16 = (u16*)(ksum + KS_F);
  u16* wq_f16t = x_f16 + XH_E;
  u16* wo_f16t = wq_f16t + WQ_E;
  const size_t needed =
      (QKV_F + 2 * F_F + KV_F + KS_F) * 4 + (XH_E + WQ_E + WO_E) * 2;

  const int MT = B_ * T_;

  if (ws_size >= needed) {
    u16* attn_f16 = x_f16;  // x_f16 dead after gemm1

    cvt_x_f16_k<<<dim3(2048), 256, 0, stream>>>(x, x_f16, MT * EMBED_ / 8);
    cvt_w_f16t_k<<<dim3(96, 32), 256, 0, stream>>>(Wqkv, wq_f16t, 3 * EMBED_);
    gemm_f16_k<<<dim3(24, 32), 256, 0, stream>>>(x_f16, wq_f16t, bqkv, qkv,
                                                 1024, 3 * EMBED_);
    features_mfma_k<<<dim3(T_ / 64, HEADS_, 4), 256, 0, stream>>>(
        qkv, omega, qnodes, qweights, qf, kf);
    chunk_sums_k<<<dim3(BH_ * NCH), 256, 0, stream>>>(kf, qkv, kvsum, ksum);
    prefix2_k<<<dim3(512), 256, 0, stream>>>(kvsum, ksum);
    cvt_w_f16t_k<<<dim3(32, 32), 256, 0, stream>>>(Wout, wo_f16t, EMBED_);
    chunk_attn4_k<<<dim3(BH_ * NCH), 256, 0, stream>>>(qf, kf, qkv, kvsum,
                                                       ksum, attn_f16);
    gemm_f16_n64_k<<<dim3(16, 32), 256, 0, stream>>>(attn_f16, wo_f16t, bout,
                                                     out, 1024, EMBED_);
  } else {
    gemm_bias_k<<<dim3(24, 32), 256, 0, stream>>>(
        x, Wqkv, bqkv, qkv, MT, 3 * EMBED_, EMBED_, EMBED_, 3 * EMBED_,
        3 * EMBED_);
    features_mfma_k<<<dim3(T_ / 64, HEADS_, 4), 256, 0, stream>>>(
        qkv, omega, qnodes, qweights, qf, kf);
    chunk_sums_k<<<dim3(BH_ * NCH), 256, 0, stream>>>(kf, qkv, kvsum, ksum);
    prefix2_k<<<dim3(512), 256, 0, stream>>>(kvsum, ksum);
    chunk_attn3_k<<<dim3(BH_ * NCH), 256, 0, stream>>>(
        qf, kf, qkv, kvsum, ksum, qkv, 3 * EMBED_);
    gemm_bias_k<<<dim3(8, 32), 256, 0, stream>>>(
        qkv, Wout, bout, out, MT, EMBED_, EMBED_, 3 * EMBED_, EMBED_, EMBED_);
  }
}

// Round 12
// 193.252 us; speedup vs baseline: 4.2123x; 1.1438x over previous
//
#include <hip/hip_runtime.h>
#include <cstddef>
#include <cstdint>

#define B_ 2
#define T_ 2048
#define EMBED_ 1024
#define HEADS_ 16
#define HD_ 64
#define M_ 32
#define R_ 2
#define FD_ 64
#define LCH 64
#define NCH (T_ / LCH)  // 32
#define BH_ (B_ * HEADS_)

typedef unsigned short u16;
using bf16x8 = __attribute__((ext_vector_type(8))) short;
using f16x8 = __attribute__((ext_vector_type(8))) _Float16;
using f32x4 = __attribute__((ext_vector_type(4))) float;

__device__ __forceinline__ u16 f2bf(float f) {
  uint32_t u = __float_as_uint(f);
  u += 0x7FFF + ((u >> 16) & 1);
  return (u16)(u >> 16);
}
__device__ __forceinline__ float bf2f(u16 h) {
  return __uint_as_float(((uint32_t)h) << 16);
}
__device__ __forceinline__ u16 f2h(float f) {
  _Float16 h = (_Float16)f;
  return *(u16*)&h;
}
__device__ __forceinline__ float h2f(u16 h) {
  return (float)(*(const _Float16*)&h);
}

__device__ __forceinline__ void gload_lds16(const void* g, void* l) {
  __builtin_amdgcn_global_load_lds(
      (const __attribute__((address_space(1))) unsigned int*)g,
      (__attribute__((address_space(3))) unsigned int*)l, 16, 0, 0);
}

// paired-row swizzle (round-5 proven: SQ_LDS_BANK_CONFLICT == 0)
__device__ __forceinline__ int swz_off(int R, int s) {
  return (R >> 1) * 64 + (((((R & 1) << 2) | s) ^ ((R >> 1) & 7)) * 8);
}

// ---------------------------------------------------------------------------
// fp16 MFMA GEMM, 128x128 tile, swizzled LDS, dbuf (round-10 proven).
// If V16 != null: columns >= 2048 are the V part -> store fp16 to V16
// ([bh][t][64]) and skip the fp32 store (nothing reads fp32 V downstream).
// ---------------------------------------------------------------------------
__global__ __launch_bounds__(256) void gemm_f16_k(
    const u16* __restrict__ A, const u16* __restrict__ Bt,
    const float* __restrict__ bias, float* __restrict__ C, int K, int ldc,
    u16* __restrict__ V16)
{
  __shared__ u16 As[2][128 * 32];
  __shared__ u16 Bs[2][128 * 32];
  const int tid = threadIdx.x;
  const int row0 = blockIdx.y * 128, col0 = blockIdx.x * 128;
  const int lane = tid & 63;
  const int w = tid >> 6;
  const int wr = tid >> 7, wc = (tid >> 6) & 1;
  f32x4 acc[4][4];
#pragma unroll
  for (int m = 0; m < 4; ++m)
#pragma unroll
    for (int n = 0; n < 4; ++n)
#pragma unroll
      for (int r = 0; r < 4; ++r) acc[m][n][r] = 0.f;

  const int u_ = (lane & 7) ^ (lane >> 3);
  const int srow = w * 16 + 2 * (lane >> 3) + (u_ >> 2);
  const int skp = (u_ & 3) * 8;
  const u16* Agp = A + (size_t)(row0 + srow) * K + skp;
  const u16* Bgp = Bt + (size_t)(col0 + srow) * K + skp;
  const int wb = w * 512;

  const int fr = lane & 15;
  const int s_ = lane >> 4;
  int aoff[4], boff[4];
#pragma unroll
  for (int m = 0; m < 4; ++m) aoff[m] = swz_off(wr * 64 + m * 16 + fr, s_);
#pragma unroll
  for (int n = 0; n < 4; ++n) boff[n] = swz_off(wc * 64 + n * 16 + fr, s_);

  const int nt = K >> 5;
  gload_lds16(Agp, &As[0][wb]);
  gload_lds16(Agp + (size_t)64 * K, &As[0][wb + 2048]);
  gload_lds16(Bgp, &Bs[0][wb]);
  gload_lds16(Bgp + (size_t)64 * K, &Bs[0][wb + 2048]);
  __syncthreads();

  for (int t = 0; t < nt; ++t) {
    const int cur = t & 1;
    if (t + 1 < nt) {
      const int k0 = (t + 1) * 32;
      gload_lds16(Agp + k0, &As[cur ^ 1][wb]);
      gload_lds16(Agp + k0 + (size_t)64 * K, &As[cur ^ 1][wb + 2048]);
      gload_lds16(Bgp + k0, &Bs[cur ^ 1][wb]);
      gload_lds16(Bgp + k0 + (size_t)64 * K, &Bs[cur ^ 1][wb + 2048]);
    }
    f16x8 a[4], b[4];
#pragma unroll
    for (int m = 0; m < 4; ++m) a[m] = *(const f16x8*)&As[cur][aoff[m]];
#pragma unroll
    for (int n = 0; n < 4; ++n) b[n] = *(const f16x8*)&Bs[cur][boff[n]];
#pragma unroll
    for (int m = 0; m < 4; ++m)
#pragma unroll
      for (int n = 0; n < 4; ++n)
        acc[m][n] = __builtin_amdgcn_mfma_f32_16x16x32_f16(a[m], b[n],
                                                           acc[m][n], 0, 0, 0);
    __syncthreads();
  }
  const int fg = lane >> 4;
#pragma unroll
  for (int m = 0; m < 4; ++m) {
#pragma unroll
    for (int n = 0; n < 4; ++n) {
      const int col = col0 + wc * 64 + n * 16 + fr;
      const float bv = bias[col];
#pragma unroll
      for (int r = 0; r < 4; ++r) {
        const int row = row0 + wr * 64 + m * 16 + fg * 4 + r;
        const float val = acc[m][n][r] + bv;
        if (V16 && col >= 2048) {
          const int bb = row >> 11, tt = row & 2047;
          const int hh = (col - 2048) >> 6, dd = col & 63;
          V16[(((size_t)bb * HEADS_ + hh) * T_ + tt) * 64 + dd] = f2h(val);
        } else {
          C[(size_t)row * ldc + col] = val;
        }
      }
    }
  }
}

// ---------------------------------------------------------------------------
// fp16 MFMA GEMM, 128x64 tile, dbuf (round-10 proven)
// ---------------------------------------------------------------------------
__global__ __launch_bounds__(256) void gemm_f16_n64_k(
    const u16* __restrict__ A, const u16* __restrict__ Bt,
    const float* __restrict__ bias, float* __restrict__ C, int K, int ldc)
{
  __shared__ u16 As[2][128 * 32];
  __shared__ u16 Bs[2][64 * 32];
  const int tid = threadIdx.x;
  const int row0 = blockIdx.y * 128, col0 = blockIdx.x * 64;
  const int lane = tid & 63;
  const int w = tid >> 6;
  f32x4 acc[2][4];
#pragma unroll
  for (int m = 0; m < 2; ++m)
#pragma unroll
    for (int n = 0; n < 4; ++n)
#pragma unroll
      for (int r = 0; r < 4; ++r) acc[m][n][r] = 0.f;

  const int u_ = (lane & 7) ^ (lane >> 3);
  const int srow = w * 16 + 2 * (lane >> 3) + (u_ >> 2);
  const int skp = (u_ & 3) * 8;
  const u16* Agp = A + (size_t)(row0 + srow) * K + skp;
  const u16* Bgp = Bt + (size_t)(col0 + srow) * K + skp;
  const int wb = w * 512;

  const int fr = lane & 15;
  const int s_ = lane >> 4;
  int aoff[2], boff[4];
#pragma unroll
  for (int m = 0; m < 2; ++m) aoff[m] = swz_off(w * 32 + m * 16 + fr, s_);
#pragma unroll
  for (int n = 0; n < 4; ++n) boff[n] = swz_off(n * 16 + fr, s_);

  const int nt = K >> 5;
  gload_lds16(Agp, &As[0][wb]);
  gload_lds16(Agp + (size_t)64 * K, &As[0][wb + 2048]);
  gload_lds16(Bgp, &Bs[0][wb]);
  __syncthreads();

  for (int t = 0; t < nt; ++t) {
    const int cur = t & 1;
    if (t + 1 < nt) {
      const int k0 = (t + 1) * 32;
      gload_lds16(Agp + k0, &As[cur ^ 1][wb]);
      gload_lds16(Agp + k0 + (size_t)64 * K, &As[cur ^ 1][wb + 2048]);
      gload_lds16(Bgp + k0, &Bs[cur ^ 1][wb]);
    }
    f16x8 a[2], b[4];
#pragma unroll
    for (int m = 0; m < 2; ++m) a[m] = *(const f16x8*)&As[cur][aoff[m]];
#pragma unroll
    for (int n = 0; n < 4; ++n) b[n] = *(const f16x8*)&Bs[cur][boff[n]];
#pragma unroll
    for (int m = 0; m < 2; ++m)
#pragma unroll
      for (int n = 0; n < 4; ++n)
        acc[m][n] = __builtin_amdgcn_mfma_f32_16x16x32_f16(a[m], b[n],
                                                           acc[m][n], 0, 0, 0);
    __syncthreads();
  }
  const int fg = lane >> 4;
#pragma unroll
  for (int m = 0; m < 2; ++m) {
#pragma unroll
    for (int n = 0; n < 4; ++n) {
      const int col = col0 + n * 16 + fr;
      const float bv = bias[col];
#pragma unroll
      for (int r = 0; r < 4; ++r) {
        const int row = row0 + w * 32 + m * 16 + fg * 4 + r;
        C[(size_t)row * ldc + col] = acc[m][n][r] + bv;
      }
    }
  }
}

// ---------------------------------------------------------------------------
// fp32 -> fp16 elementwise convert (8 elems/thread)
// ---------------------------------------------------------------------------
__global__ __launch_bounds__(256) void cvt_x_f16_k(const float* __restrict__ X,
                                                   u16* __restrict__ Y, int n8)
{
  const int idx = blockIdx.x * 256 + threadIdx.x;
  if (idx >= n8) return;
  float4 a = *(const float4*)&X[(size_t)idx * 8];
  float4 b = *(const float4*)&X[(size_t)idx * 8 + 4];
  ushort4 o0, o1;
  o0.x = f2h(a.x); o0.y = f2h(a.y); o0.z = f2h(a.z); o0.w = f2h(a.w);
  o1.x = f2h(b.x); o1.y = f2h(b.y); o1.z = f2h(b.z); o1.w = f2h(b.w);
  *(ushort4*)&Y[(size_t)idx * 8] = o0;
  *(ushort4*)&Y[(size_t)idx * 8 + 4] = o1;
}

// ---------------------------------------------------------------------------
// transpose + convert W [1024][N] fp32 -> Wt [N][1024] fp16
// ---------------------------------------------------------------------------
__global__ __launch_bounds__(256) void cvt_w_f16t_k(const float* __restrict__ W,
                                                    u16* __restrict__ Wt, int N)
{
  __shared__ float tile[32][33];
  const int n0 = blockIdx.x * 32, k0 = blockIdx.y * 32;
  const int tx = threadIdx.x & 31, ty = threadIdx.x >> 5;
#pragma unroll
  for (int i = 0; i < 4; ++i)
    tile[ty + i * 8][tx] = W[(size_t)(k0 + ty + i * 8) * N + n0 + tx];
  __syncthreads();
#pragma unroll
  for (int i = 0; i < 4; ++i) {
    const int n = ty + i * 8;
    Wt[(size_t)(n0 + n) * 1024 + k0 + tx] = f2h(tile[tx][n]);
  }
}

// ---------------------------------------------------------------------------
// fallback fp32 GEMM (round-1, proven)
// ---------------------------------------------------------------------------
__global__ __launch_bounds__(256) void gemm_bias_k(
    const float* __restrict__ A, const float* __restrict__ Bm,
    const float* __restrict__ bias, float* __restrict__ C,
    int Mdim, int Ndim, int Kdim, int lda, int ldb, int ldc)
{
  __shared__ float Asm[16][128];
  __shared__ float Bsm[16][128];
  const int tid = threadIdx.x;
  const int row0 = blockIdx.y * 128;
  const int col0 = blockIdx.x * 128;
  const int ty = tid >> 4, tx = tid & 15;
  float acc[8][8];
#pragma unroll
  for (int i = 0; i < 8; ++i)
#pragma unroll
    for (int j = 0; j < 8; ++j) acc[i][j] = 0.f;

  for (int k0 = 0; k0 < Kdim; k0 += 16) {
#pragma unroll
    for (int l = 0; l < 2; ++l) {
      int f = tid * 2 + l;
      int ar = f >> 2, aq = f & 3;
      float4 av = *reinterpret_cast<const float4*>(
          &A[(size_t)(row0 + ar) * lda + k0 + aq * 4]);
      Asm[aq * 4 + 0][ar] = av.x;
      Asm[aq * 4 + 1][ar] = av.y;
      Asm[aq * 4 + 2][ar] = av.z;
      Asm[aq * 4 + 3][ar] = av.w;
      int br = f >> 5, bc = f & 31;
      *reinterpret_cast<float4*>(&Bsm[br][bc * 4]) =
          *reinterpret_cast<const float4*>(
              &Bm[(size_t)(k0 + br) * ldb + col0 + bc * 4]);
    }
    __syncthreads();
#pragma unroll
    for (int kk = 0; kk < 16; ++kk) {
      float a[8], b[8];
      *reinterpret_cast<float4*>(&a[0]) =
          *reinterpret_cast<const float4*>(&Asm[kk][ty * 8]);
      *reinterpret_cast<float4*>(&a[4]) =
          *reinterpret_cast<const float4*>(&Asm[kk][ty * 8 + 4]);
      *reinterpret_cast<float4*>(&b[0]) =
          *reinterpret_cast<const float4*>(&Bsm[kk][tx * 8]);
      *reinterpret_cast<float4*>(&b[4]) =
          *reinterpret_cast<const float4*>(&Bsm[kk][tx * 8 + 4]);
#pragma unroll
      for (int i = 0; i < 8; ++i)
#pragma unroll
        for (int j = 0; j < 8; ++j) acc[i][j] += a[i] * b[j];
    }
    __syncthreads();
  }
#pragma unroll
  for (int i = 0; i < 8; ++i) {
    int r = row0 + ty * 8 + i;
#pragma unroll
    for (int j = 0; j < 8; j += 4) {
      int c = col0 + tx * 8 + j;
      float4 o;
      o.x = acc[i][j + 0] + bias[c + 0];
      o.y = acc[i][j + 1] + bias[c + 1];
      o.z = acc[i][j + 2] + bias[c + 2];
      o.w = acc[i][j + 3] + bias[c + 3];
      *reinterpret_cast<float4*>(&C[(size_t)r * ldc + c]) = o;
    }
  }
}

// ---------------------------------------------------------------------------
// Laplace features via MFMA (bf16 hi/lo, K_ext=192); fp16 or fp32 output.
// ---------------------------------------------------------------------------
__global__ __launch_bounds__(256) void features_mfma_k(
    const float* __restrict__ qkv, const float* __restrict__ omega,
    const float* __restrict__ qnodes, const float* __restrict__ qweights,
    void* __restrict__ qfv, void* __restrict__ kfv, int f16out)
{
  __shared__ u16 Aext[64 * 200];
  __shared__ u16 Bext[64 * 200];
  __shared__ float rinv_s[64];
  const int tid = threadIdx.x;
  const int t0 = blockIdx.x * 64;
  const int h = blockIdx.y;
  const int b = blockIdx.z & 1;
  const int which = blockIdx.z >> 1;
  const int bh = b * HEADS_ + h;

  {
    const int row = tid >> 2;
    const int seg = (tid & 3) * 16;
    const float* xsrc = &qkv[((size_t)(b * T_ + t0 + row)) * 3072 +
                             which * 1024 + h * 64 + seg];
    float xv[16];
#pragma unroll
    for (int q = 0; q < 4; ++q)
      *(float4*)&xv[q * 4] = *(const float4*)&xsrc[q * 4];
    float ss = 0.f;
#pragma unroll
    for (int j = 0; j < 16; ++j) ss += xv[j] * xv[j];
    ss += __shfl_xor(ss, 1, 64);
    ss += __shfl_xor(ss, 2, 64);
    if ((tid & 3) == 0) rinv_s[row] = 1.f / fmaxf(sqrtf(ss), 1e-12f);
    ushort4 hv[4], lv[4];
    u16* hp = (u16*)hv; u16* lp = (u16*)lv;
#pragma unroll
    for (int j = 0; j < 16; ++j) {
      u16 hh = f2bf(xv[j]);
      hp[j] = hh;
      lp[j] = f2bf(xv[j] - bf2f(hh));
    }
    u16* arow = &Aext[row * 200 + seg];
#pragma unroll
    for (int q = 0; q < 4; ++q) {
      *(ushort4*)&arow[q * 4] = hv[q];
      *(ushort4*)&arow[64 + q * 4] = lv[q];
      *(ushort4*)&arow[128 + q * 4] = hv[q];
    }
  }
  {
    const int r_o = tid >> 7;
    const int dseg = (tid >> 5) & 3;
    const int m_o = tid & 31;
    const int n = r_o * 32 + m_o;
    const size_t obase =
        (((size_t)(r_o * HEADS_ + h)) * HD_ + dseg * 16) * M_ + m_o;
    ushort4 hv[4], lv[4];
    u16* hp = (u16*)hv; u16* lp = (u16*)lv;
#pragma unroll
    for (int i = 0; i < 16; ++i) {
      float v = omega[obase + (size_t)i * M_];
      u16 hh = f2bf(v);
      hp[i] = hh;
      lp[i] = f2bf(v - bf2f(hh));
    }
    u16* brow = &Bext[n * 200 + dseg * 16];
#pragma unroll
    for (int q = 0; q < 4; ++q) {
      *(ushort4*)&brow[q * 4] = hv[q];
      *(ushort4*)&brow[64 + q * 4] = hv[q];
      *(ushort4*)&brow[128 + q * 4] = lv[q];
    }
  }
  __syncthreads();

  const int lane = tid & 63;
  const int w = tid >> 6;
  const int fr = lane & 15, s_ = lane >> 4;
  f32x4 facc[4];
#pragma unroll
  for (int n = 0; n < 4; ++n)
#pragma unroll
    for (int r = 0; r < 4; ++r) facc[n][r] = 0.f;
  const u16* arow = &Aext[(w * 16 + fr) * 200 + s_ * 8];
#pragma unroll
  for (int kk = 0; kk < 6; ++kk) {
    bf16x8 av = *(const bf16x8*)&arow[kk * 32];
#pragma unroll
    for (int n = 0; n < 4; ++n) {
      bf16x8 bv = *(const bf16x8*)&Bext[(n * 16 + fr) * 200 + kk * 32 + s_ * 8];
      facc[n] = __builtin_amdgcn_mfma_f32_16x16x32_bf16(av, bv, facc[n], 0, 0, 0);
    }
  }

  const float s0 = qnodes[0], s1 = qnodes[1];
  const float sq0 = sqrtf(2.f * fmaxf(s0, 0.f));
  const float sq1 = sqrtf(2.f * fmaxf(s1, 0.f));
  const float sc0 = sqrtf(fmaxf(qweights[0], 0.f)) * 0.17677669529663687f;
  const float sc1 = sqrtf(fmaxf(qweights[1], 0.f)) * 0.17677669529663687f;
  void* dstv = which ? kfv : qfv;
  const size_t base = ((size_t)bh * T_ + t0) * FD_;
  const int fg = lane >> 4;
#pragma unroll
  for (int n = 0; n < 4; ++n) {
    const int feat = n * 16 + fr;
    const int ridx = n >> 1;
    const float sq = ridx ? sq1 : sq0;
    const float so = ridx ? s1 : s0;
    const float sc = ridx ? sc1 : sc0;
#pragma unroll
    for (int j = 0; j < 4; ++j) {
      const int token = w * 16 + fg * 4 + j;
      const float pr = facc[n][j] * rinv_s[token];
      float arg = fminf(fmaxf(pr * sq - so, -20.f), 20.f);
      const float val = expf(arg) * sc;
      if (f16out)
        ((u16*)dstv)[base + (size_t)token * FD_ + feat] = f2h(val);
      else
        ((float*)dstv)[base + (size_t)token * FD_ + feat] = val;
    }
  }
}

// ---------------------------------------------------------------------------
// MFMA per-chunk KV = kf^T @ v (fp16 in, fp32 out) + ksum. Transposed fp16
// LDS staging (stride 72, attn4-proven pattern); 8 MFMA/wave.
// ---------------------------------------------------------------------------
__global__ __launch_bounds__(256) void chunk_sums_f16_k(
    const u16* __restrict__ kf16, const u16* __restrict__ v16,
    float* __restrict__ kvsum, float* __restrict__ ksum)
{
  __shared__ u16 kfT[64 * 72];  // [f][t]
  __shared__ u16 vT[64 * 72];   // [d][t]
  const int blk = blockIdx.x;
  const int c = blk & (NCH - 1);
  const int bh = blk / NCH;
  const int tid = threadIdx.x;
  {
    const int r = tid >> 2, q4 = (tid & 3) * 16;
    const u16* kp = &kf16[((size_t)bh * T_ + c * LCH + r) * 64 + q4];
    const u16* vp = &v16[((size_t)bh * T_ + c * LCH + r) * 64 + q4];
    u16 kv[16], vv[16];
    *(uint4*)&kv[0] = *(const uint4*)&kp[0];
    *(uint4*)&kv[8] = *(const uint4*)&kp[8];
    *(uint4*)&vv[0] = *(const uint4*)&vp[0];
    *(uint4*)&vv[8] = *(const uint4*)&vp[8];
#pragma unroll
    for (int j = 0; j < 16; ++j) {
      kfT[(q4 + j) * 72 + r] = kv[j];
      vT[(q4 + j) * 72 + r] = vv[j];
    }
  }
  __syncthreads();

  if (tid < 64) {
    const _Float16* rp = (const _Float16*)&kfT[tid * 72];
    float s = 0.f;
#pragma unroll
    for (int i = 0; i < 8; ++i) {
      f16x8 vv = *(const f16x8*)&rp[i * 8];
#pragma unroll
      for (int j = 0; j < 8; ++j) s += (float)vv[j];
    }
    ksum[(size_t)blk * 64 + tid] = s;
  }

  const int lane = tid & 63;
  const int w = tid >> 6;
  const int fr = lane & 15, s_ = lane >> 4;
  const f16x8 a0 = *(const f16x8*)&kfT[(w * 16 + fr) * 72 + s_ * 8];
  const f16x8 a1 = *(const f16x8*)&kfT[(w * 16 + fr) * 72 + 32 + s_ * 8];
  f32x4 acc[4];
#pragma unroll
  for (int n = 0; n < 4; ++n) {
#pragma unroll
    for (int r = 0; r < 4; ++r) acc[n][r] = 0.f;
    const f16x8 b0 = *(const f16x8*)&vT[(n * 16 + fr) * 72 + s_ * 8];
    const f16x8 b1 = *(const f16x8*)&vT[(n * 16 + fr) * 72 + 32 + s_ * 8];
    acc[n] = __builtin_amdgcn_mfma_f32_16x16x32_f16(a0, b0, acc[n], 0, 0, 0);
    acc[n] = __builtin_amdgcn_mfma_f32_16x16x32_f16(a1, b1, acc[n], 0, 0, 0);
  }
#pragma unroll
  for (int n = 0; n < 4; ++n) {
    const int d = n * 16 + fr;
#pragma unroll
    for (int r = 0; r < 4; ++r) {
      const int f = w * 16 + s_ * 4 + r;
      kvsum[(size_t)blk * 4096 + (size_t)f * 64 + d] = acc[n][r];
    }
  }
}

// ---------------------------------------------------------------------------
// fallback per-chunk KV (fp32, round-10 proven)
// ---------------------------------------------------------------------------
__global__ __launch_bounds__(256) void chunk_sums_k(
    const float* __restrict__ kf, const float* __restrict__ qkv,
    float* __restrict__ kvsum, float* __restrict__ ksum)
{
  const int blk = blockIdx.x;
  const int c = blk % NCH;
  const int bh = blk / NCH;
  const int b = bh / HEADS_, h = bh % HEADS_;
  const int tid = threadIdx.x;
  const int d = tid & 63;
  const int fq = tid >> 6;
  __shared__ float kf_s[16][64];
  __shared__ float v_s[16][64];
  float acc[16];
#pragma unroll
  for (int i = 0; i < 16; ++i) acc[i] = 0.f;
  float ks = 0.f;
  for (int t0 = 0; t0 < LCH; t0 += 16) {
#pragma unroll
    for (int l = 0; l < 4; ++l) {
      int idx = tid + l * 256;
      int rr = idx >> 6, cc = idx & 63;
      int t = c * LCH + t0 + rr;
      kf_s[rr][cc] = kf[((size_t)bh * T_ + t) * FD_ + cc];
      v_s[rr][cc] =
          qkv[((size_t)(b * T_ + t)) * 3072 + 2 * EMBED_ + h * HD_ + cc];
    }
    __syncthreads();
#pragma unroll
    for (int tt = 0; tt < 16; ++tt) {
      float vv = v_s[tt][d];
      if (fq == 0) ks += kf_s[tt][d];
#pragma unroll
      for (int i = 0; i < 16; ++i) acc[i] += kf_s[tt][fq * 16 + i] * vv;
    }
    __syncthreads();
  }
#pragma unroll
  for (int i = 0; i < 16; ++i)
    kvsum[(size_t)blk * 4096 + (size_t)(fq * 16 + i) * 64 + d] = acc[i];
  if (fq == 0) ksum[(size_t)blk * 64 + d] = ks;
}

// ---------------------------------------------------------------------------
// Exclusive prefix over chunks — register-resident, 512 blocks
// ---------------------------------------------------------------------------
__global__ __launch_bounds__(256) void prefix2_k(float* __restrict__ kvsum,
                                                 float* __restrict__ ksum)
{
  const int bh = blockIdx.x >> 4;
  const int eb = blockIdx.x & 15;
  const int e = eb * 256 + threadIdx.x;
  float v[NCH];
  const size_t base = (size_t)bh * NCH * 4096 + e;
#pragma unroll
  for (int c = 0; c < NCH; ++c) v[c] = kvsum[base + (size_t)c * 4096];
  float run = 0.f;
#pragma unroll
  for (int c = 0; c < NCH; ++c) {
    kvsum[base + (size_t)c * 4096] = run;
    run += v[c];
  }
  if (eb == 0 && threadIdx.x < 64) {
    const size_t kb = (size_t)bh * NCH * 64 + threadIdx.x;
    float w[NCH];
#pragma unroll
    for (int c = 0; c < NCH; ++c) w[c] = ksum[kb + c * 64];
    float r2 = 0.f;
#pragma unroll
    for (int c = 0; c < NCH; ++c) {
      ksum[kb + c * 64] = r2;
      r2 += w[c];
    }
  }
}

// ---------------------------------------------------------------------------
// MFMA per-chunk causal attention (round-11 proven structure), fp16 inputs.
// ---------------------------------------------------------------------------
__global__ __launch_bounds__(256) void chunk_attn4_k(
    const u16* __restrict__ qf16, const u16* __restrict__ kf16,
    const u16* __restrict__ v16, const float* __restrict__ kvsum,
    const float* __restrict__ ksum, u16* __restrict__ out_f16)
{
  constexpr float SCL = 1.f / 1024.f;
  constexpr float DEN_EPS = 1e-6f / 1024.f;
  __shared__ u16 qf_h[64 * 72];
  __shared__ u16 kf_h[64 * 72];
  __shared__ u16 st_h[64 * 72];  // S^T [d][f], scaled
  __shared__ u16 vt_h[64 * 72];  // V^T [d][s]
  __shared__ u16 p_h[64 * 72];   // P   [t][s], scaled
  __shared__ float den_s[64];
  const int blk = blockIdx.x;
  const int c = blk & (NCH - 1);
  const int bh = blk / NCH;
  const int b = bh / HEADS_, h = bh % HEADS_;
  const int tid = threadIdx.x;

  {
    const int r = tid >> 2, q4 = (tid & 3) * 16;
    const size_t fbase = ((size_t)bh * T_ + c * LCH + r) * 64 + q4;
    const size_t sbase = (size_t)blk * 4096 + (size_t)r * 64 + q4;
    u16 qv[16], kv[16], vv[16];
    *(uint4*)&qv[0] = *(const uint4*)&qf16[fbase];
    *(uint4*)&qv[8] = *(const uint4*)&qf16[fbase + 8];
    *(uint4*)&kv[0] = *(const uint4*)&kf16[fbase];
    *(uint4*)&kv[8] = *(const uint4*)&kf16[fbase + 8];
    *(uint4*)&vv[0] = *(const uint4*)&v16[fbase];
    *(uint4*)&vv[8] = *(const uint4*)&v16[fbase + 8];
    float sv[16], ks[16];
#pragma unroll
    for (int j = 0; j < 16; j += 4) {
      *(float4*)&sv[j] = *(const float4*)&kvsum[sbase + j];
      *(float4*)&ks[j] = *(const float4*)&ksum[(size_t)blk * 64 + q4 + j];
    }
    float dh = 0.f;
#pragma unroll
    for (int j = 0; j < 16; ++j) dh += h2f(qv[j]) * ks[j];
    dh += __shfl_xor(dh, 1, 64);
    dh += __shfl_xor(dh, 2, 64);
    if ((tid & 3) == 0) den_s[r] = dh * SCL;
    *(uint4*)&qf_h[r * 72 + q4] = *(const uint4*)&qv[0];
    *(uint4*)&qf_h[r * 72 + q4 + 8] = *(const uint4*)&qv[8];
    *(uint4*)&kf_h[r * 72 + q4] = *(const uint4*)&kv[0];
    *(uint4*)&kf_h[r * 72 + q4 + 8] = *(const uint4*)&kv[8];
#pragma unroll
    for (int j = 0; j < 16; ++j) {
      st_h[(q4 + j) * 72 + r] = f2h(sv[j] * SCL);
      vt_h[(q4 + j) * 72 + r] = vv[j];
    }
  }
  __syncthreads();

  const int lane = tid & 63;
  const int w = tid >> 6;
  const int fr = lane & 15;
  const int s_ = lane >> 4;
  const int arow = (w * 16 + fr) * 72 + s_ * 8;
  const int trow = w * 16 + s_ * 4;

  const f16x8 a0 = *(const f16x8*)&qf_h[arow];
  const f16x8 a1 = *(const f16x8*)&qf_h[arow + 32];

  f32x4 sc[4];
#pragma unroll
  for (int n = 0; n < 4; ++n) {
#pragma unroll
    for (int r = 0; r < 4; ++r) sc[n][r] = 0.f;
    const f16x8 b0 = *(const f16x8*)&kf_h[(n * 16 + fr) * 72 + s_ * 8];
    const f16x8 b1 = *(const f16x8*)&kf_h[(n * 16 + fr) * 72 + 32 + s_ * 8];
    sc[n] = __builtin_amdgcn_mfma_f32_16x16x32_f16(a0, b0, sc[n], 0, 0, 0);
    sc[n] = __builtin_amdgcn_mfma_f32_16x16x32_f16(a1, b1, sc[n], 0, 0, 0);
  }
  f32x4 acc[4];
#pragma unroll
  for (int n = 0; n < 4; ++n) {
#pragma unroll
    for (int r = 0; r < 4; ++r) acc[n][r] = 0.f;
    const f16x8 b0 = *(const f16x8*)&st_h[(n * 16 + fr) * 72 + s_ * 8];
    const f16x8 b1 = *(const f16x8*)&st_h[(n * 16 + fr) * 72 + 32 + s_ * 8];
    acc[n] = __builtin_amdgcn_mfma_f32_16x16x32_f16(a0, b0, acc[n], 0, 0, 0);
    acc[n] = __builtin_amdgcn_mfma_f32_16x16x32_f16(a1, b1, acc[n], 0, 0, 0);
  }
  float den2[4] = {0.f, 0.f, 0.f, 0.f};
#pragma unroll
  for (int n = 0; n < 4; ++n) {
    const int scol = n * 16 + fr;
#pragma unroll
    for (int r = 0; r < 4; ++r) {
      const int t = trow + r;
      const float v = (scol <= t) ? sc[n][r] : 0.f;
      p_h[t * 72 + scol] = f2h(v * SCL);
      den2[r] += v;
    }
  }
#pragma unroll
  for (int r = 0; r < 4; ++r) {
    float d = den2[r];
    d += __shfl_xor(d, 1, 64);
    d += __shfl_xor(d, 2, 64);
    d += __shfl_xor(d, 4, 64);
    d += __shfl_xor(d, 8, 64);
    den2[r] = d;
  }
  if (fr == 0) {
#pragma unroll
    for (int r = 0; r < 4; ++r) den_s[trow + r] += den2[r] * SCL;
  }
  __syncthreads();

  const f16x8 p0 = *(const f16x8*)&p_h[arow];
  const f16x8 p1 = *(const f16x8*)&p_h[arow + 32];
#pragma unroll
  for (int n = 0; n < 4; ++n) {
    const f16x8 b0 = *(const f16x8*)&vt_h[(n * 16 + fr) * 72 + s_ * 8];
    const f16x8 b1 = *(const f16x8*)&vt_h[(n * 16 + fr) * 72 + 32 + s_ * 8];
    acc[n] = __builtin_amdgcn_mfma_f32_16x16x32_f16(p0, b0, acc[n], 0, 0, 0);
    acc[n] = __builtin_amdgcn_mfma_f32_16x16x32_f16(p1, b1, acc[n], 0, 0, 0);
  }

  float rden[4];
#pragma unroll
  for (int r = 0; r < 4; ++r)
    rden[r] = 1.f / fmaxf(den_s[trow + r], DEN_EPS);
#pragma unroll
  for (int n = 0; n < 4; ++n) {
    const int d = n * 16 + fr;
#pragma unroll
    for (int r = 0; r < 4; ++r) {
      const int t = trow + r;
      out_f16[((size_t)(b * T_ + c * LCH + t)) * 1024 + h * HD_ + d] =
          f2h(acc[n][r] * rden[r]);
    }
  }
}

// ---------------------------------------------------------------------------
// fallback per-chunk causal attention (fp32, round-10 proven)
// ---------------------------------------------------------------------------
__global__ __launch_bounds__(256) void chunk_attn3_k(
    const float* __restrict__ qf, const float* __restrict__ kf,
    const float* __restrict__ qkv_v, const float* __restrict__ kvsum,
    const float* __restrict__ ksum, float* __restrict__ out_f32, int lda)
{
  const int blk = blockIdx.x;
  const int c = blk & (NCH - 1);
  const int bh = blk / NCH;
  const int b = bh / HEADS_, h = bh % HEADS_;
  const int tid = threadIdx.x;
  __shared__ float kf_s[64][64];
  __shared__ float v_s[64][64];
  __shared__ float S_s[64][64];
  __shared__ float qf_s[64][64];
  {
    const int r = tid >> 2, q4 = (tid & 3) * 16;
    const size_t fbase = ((size_t)bh * T_ + c * LCH + r) * FD_ + q4;
    const size_t vbase =
        ((size_t)(b * T_ + c * LCH + r)) * 3072 + 2 * EMBED_ + h * HD_ + q4;
    const size_t sbase = (size_t)blk * 4096 + (size_t)r * 64 + q4;
#pragma unroll
    for (int j = 0; j < 16; j += 4) {
      *(float4*)&kf_s[r][q4 + j] = *(const float4*)&kf[fbase + j];
      *(float4*)&qf_s[r][q4 + j] = *(const float4*)&qf[fbase + j];
      *(float4*)&S_s[r][q4 + j] = *(const float4*)&kvsum[sbase + j];
      *(float4*)&v_s[r][q4 + j] = *(const float4*)&qkv_v[vbase + j];
    }
  }
  __syncthreads();
  const int l = tid & 63;
  const int t = (tid >> 6) * 16 + (l & 15);
  const int dq = l >> 4, d0 = dq * 16;

  float q_r[64];
#pragma unroll
  for (int j = 0; j < 64; j += 4)
    *(float4*)&q_r[j] = *(const float4*)&qf_s[t][j];

  float ctx[16];
#pragma unroll
  for (int j = 0; j < 16; ++j) ctx[j] = 0.f;
  float den = 0.f, den2 = 0.f;

#pragma unroll 4
  for (int f = 0; f < 64; ++f) {
    const float qv = q_r[f];
#pragma unroll
    for (int j = 0; j < 16; j += 4) {
      float4 s4 = *(const float4*)&S_s[f][d0 + j];
      ctx[j + 0] += qv * s4.x;
      ctx[j + 1] += qv * s4.y;
      ctx[j + 2] += qv * s4.z;
      ctx[j + 3] += qv * s4.w;
    }
  }
  {
    const float* svp = &ksum[(size_t)blk * 64 + d0];
#pragma unroll
    for (int j = 0; j < 16; ++j) den += q_r[d0 + j] * svp[j];
  }

  for (int s = 0; s < LCH; ++s) {
    float a = 0.f;
#pragma unroll
    for (int j = 0; j < 16; j += 4) {
      float4 k4 = *(const float4*)&kf_s[s][d0 + j];
      a += q_r[d0 + j] * k4.x + q_r[d0 + j + 1] * k4.y +
           q_r[d0 + j + 2] * k4.z + q_r[d0 + j + 3] * k4.w;
    }
    a += __shfl_xor(a, 16, 64);
    a += __shfl_xor(a, 32, 64);
    if (s <= t) {
      den2 += a;
#pragma unroll
      for (int j = 0; j < 16; j += 4) {
        float4 v4 = *(const float4*)&v_s[s][d0 + j];
        ctx[j + 0] += a * v4.x;
        ctx[j + 1] += a * v4.y;
        ctx[j + 2] += a * v4.z;
        ctx[j + 3] += a * v4.w;
      }
    }
  }
  den += __shfl_xor(den, 16, 64);
  den += __shfl_xor(den, 32, 64);
  const float rden = 1.f / fmaxf(den + den2, 1e-6f);
  float* op = &out_f32[((size_t)(b * T_ + c * LCH + t)) * lda + h * HD_ + d0];
#pragma unroll
  for (int j = 0; j < 16; j += 4) {
    float4 o;
    o.x = ctx[j + 0] * rden;
    o.y = ctx[j + 1] * rden;
    o.z = ctx[j + 2] * rden;
    o.w = ctx[j + 3] * rden;
    *(float4*)&op[j] = o;
  }
}

// ---------------------------------------------------------------------------
extern "C" void kernel_launch(void* const* d_in, const int* in_sizes, int n_in,
                              void* d_out, int out_size, void* d_ws,
                              size_t ws_size, hipStream_t stream)
{
  (void)in_sizes; (void)n_in; (void)out_size;
  const float* x = (const float*)d_in[0];
  const float* Wqkv = (const float*)d_in[1];
  const float* bqkv = (const float*)d_in[2];
  const float* Wout = (const float*)d_in[3];
  const float* bout = (const float*)d_in[4];
  const float* omega = (const float*)d_in[5];
  const float* qnodes = (const float*)d_in[6];
  const float* qweights = (const float*)d_in[7];
  float* out = (float*)d_out;

  float* ws = (float*)d_ws;
  const size_t QKV_F = (size_t)B_ * T_ * 3 * EMBED_;   // 12,582,912
  const size_t F_F = (size_t)BH_ * T_ * FD_;           // 4,194,304
  const size_t KV_F = (size_t)BH_ * NCH * FD_ * HD_;   // 4,194,304
  const size_t KS_F = (size_t)BH_ * NCH * FD_;         // 65,536
  const size_t XH_E = (size_t)B_ * T_ * EMBED_;        // 4,194,304 u16
  const size_t WQ_E = (size_t)3 * EMBED_ * EMBED_;     // 3,145,728 u16
  const size_t WO_E = (size_t)EMBED_ * EMBED_;         // 1,048,576 u16

  const int MT = B_ * T_;

  // main-path layout (qf/kf/v fp16)
  float* qkv = ws;
  u16* qf16 = (u16*)(qkv + QKV_F);
  u16* kf16 = qf16 + F_F;
  u16* v16 = kf16 + F_F;
  float* kvsum = (float*)(v16 + F_F);
  float* ksum = kvsum + KV_F;
  u16* x_f16 = (u16*)(ksum + KS_F);
  u16* wq_f16t = x_f16 + XH_E;
  u16* wo_f16t = wq_f16t + WQ_E;
  const size_t needed = QKV_F * 4 + 3 * F_F * 2 + (KV_F + KS_F) * 4 +
                        (XH_E + WQ_E + WO_E) * 2;

  if (ws_size >= needed) {
    u16* attn_f16 = x_f16;  // x_f16 dead after gemm1

    cvt_x_f16_k<<<dim3(2048), 256, 0, stream>>>(x, x_f16, MT * EMBED_ / 8);
    cvt_w_f16t_k<<<dim3(96, 32), 256, 0, stream>>>(Wqkv, wq_f16t, 3 * EMBED_);
    gemm_f16_k<<<dim3(24, 32), 256, 0, stream>>>(x_f16, wq_f16t, bqkv, qkv,
                                                 1024, 3 * EMBED_, v16);
    features_mfma_k<<<dim3(T_ / 64, HEADS_, 4), 256, 0, stream>>>(
        qkv, omega, qnodes, qweights, qf16, kf16, 1);
    chunk_sums_f16_k<<<dim3(BH_ * NCH), 256, 0, stream>>>(kf16, v16, kvsum,
                                                          ksum);
    prefix2_k<<<dim3(512), 256, 0, stream>>>(kvsum, ksum);
    cvt_w_f16t_k<<<dim3(32, 32), 256, 0, stream>>>(Wout, wo_f16t, EMBED_);
    chunk_attn4_k<<<dim3(BH_ * NCH), 256, 0, stream>>>(qf16, kf16, v16, kvsum,
                                                       ksum, attn_f16);
    gemm_f16_n64_k<<<dim3(16, 32), 256, 0, stream>>>(attn_f16, wo_f16t, bout,
                                                     out, 1024, EMBED_);
  } else {
    // fallback layout (fp32 qf/kf, v inside qkv)
    float* qf = qkv + QKV_F;
    float* kf = qf + F_F;
    float* kvs = kf + F_F;
    float* kss = kvs + KV_F;
    gemm_bias_k<<<dim3(24, 32), 256, 0, stream>>>(
        x, Wqkv, bqkv, qkv, MT, 3 * EMBED_, EMBED_, EMBED_, 3 * EMBED_,
        3 * EMBED_);
    features_mfma_k<<<dim3(T_ / 64, HEADS_, 4), 256, 0, stream>>>(
        qkv, omega, qnodes, qweights, qf, kf, 0);
    chunk_sums_k<<<dim3(BH_ * NCH), 256, 0, stream>>>(kf, qkv, kvs, kss);
    prefix2_k<<<dim3(512), 256, 0, stream>>>(kvs, kss);
    chunk_attn3_k<<<dim3(BH_ * NCH), 256, 0, stream>>>(
        qf, kf, qkv, kvs, kss, qkv, 3 * EMBED_);
    gemm_bias_k<<<dim3(8, 32), 256, 0, stream>>>(
        qkv, Wout, bout, out, MT, EMBED_, EMBED_, 3 * EMBED_, EMBED_, EMBED_);
  }
}